// Round 1
// baseline (1196.910 us; speedup 1.0000x reference)
//
#include <hip/hip_runtime.h>
#include <math.h>

#define B_ 8
#define S_ 2048
#define F_ 64
#define D_ 512
#define NS_ 5
#define BS_ (B_*S_)

// ws layout (float offsets)
#define WS_Q      0
#define WS_K      (WS_Q + BS_*F_)
#define WS_SQ     (WS_K + BS_*F_)
#define WS_INV    (WS_SQ + BS_)
#define WS_REL    (WS_INV + BS_)
#define WS_PE     (WS_REL + BS_*3)
#define WS_STATS  (WS_PE + BS_*F_)   // byte offset 12910592, 8-aligned
// stats: [0:2) double sum, [2:4) double sumsq, [4] uint minbits, [5] uint maxbits, params at +8

__device__ __forceinline__ unsigned fmap_(float f){
  unsigned u = __float_as_uint(f);
  return (u & 0x80000000u) ? ~u : (u | 0x80000000u);
}
__device__ __forceinline__ float funmap_(unsigned u){
  return (u & 0x80000000u) ? __uint_as_float(u ^ 0x80000000u) : __uint_as_float(~u);
}
// swizzled row-major [64][64] tile: element (row,f) at row*64 + ((f4chunk ^ (row&15))<<2) + (f&3)
__device__ __forceinline__ int swz_phys(int row, int c){ return row*64 + (((c ^ (row & 15))) << 2); }

#define COMP(v,i) ((i)==0?(v).x:((i)==1?(v).y:((i)==2?(v).z:(v).w)))

__global__ void k0_init(float* ws){
  double* dp = (double*)(ws + WS_STATS);
  dp[0] = 0.0; dp[1] = 0.0;
  unsigned* up = (unsigned*)(ws + WS_STATS + 4);
  up[0] = 0xFFFFFFFFu; up[1] = 0u;
}

// K1: q = x@wq^T + bq, k = x@wk^T + bk, sq = ||x||^2, inv_norm, rel_sum (5-scale sums)
__global__ __launch_bounds__(256) void k1_prep(
    const float* __restrict__ x, const float* __restrict__ wq, const float* __restrict__ bq,
    const float* __restrict__ wk, const float* __restrict__ bk,
    const float* __restrict__ scale_w, float* __restrict__ ws)
{
  __shared__ __align__(16) float xl[16*68];
  __shared__ __align__(16) float wql[4096];
  __shared__ __align__(16) float wkl[4096];
  int tid = threadIdx.x, lane = tid & 63, wv = tid >> 6;
  int row0 = blockIdx.x * 16;
  {
    int r = tid >> 4, c = tid & 15;
    *(float4*)(xl + r*68 + c*4) = *(const float4*)(x + (size_t)(row0 + r)*F_ + c*4);
  }
  for (int i = 0; i < 4; ++i){
    int idx = tid + i*256;
    int g = idx >> 4, c = idx & 15;
    float4 v = *(const float4*)(wq + g*F_ + c*4);
    int pb = swz_phys(g, c);
    wql[pb]=v.x; wql[pb+1]=v.y; wql[pb+2]=v.z; wql[pb+3]=v.w;
    float4 u = *(const float4*)(wk + g*F_ + c*4);
    wkl[pb]=u.x; wkl[pb+1]=u.y; wkl[pb+2]=u.z; wkl[pb+3]=u.w;
  }
  __syncthreads();
  int g = lane;
  int swl = g & 15;
  float qa[4], ka[4];
  #pragma unroll
  for (int j=0;j<4;++j){ qa[j]=bq[g]; ka[j]=bk[g]; }
  #pragma unroll
  for (int c=0;c<16;++c){
    float4 wqv = *(const float4*)(wql + g*64 + ((c ^ swl)<<2));
    float4 wkv = *(const float4*)(wkl + g*64 + ((c ^ swl)<<2));
    #pragma unroll
    for (int j=0;j<4;++j){
      float4 xv = *(const float4*)(xl + (wv*4+j)*68 + c*4);
      qa[j] += xv.x*wqv.x + xv.y*wqv.y + xv.z*wqv.z + xv.w*wqv.w;
      ka[j] += xv.x*wkv.x + xv.y*wkv.y + xv.z*wkv.z + xv.w*wkv.w;
    }
  }
  #pragma unroll
  for (int j=0;j<4;++j){
    int rg = row0 + wv*4 + j;
    ws[WS_Q + rg*F_ + g] = qa[j];
    ws[WS_K + rg*F_ + g] = ka[j];
  }
  #pragma unroll
  for (int j=0;j<4;++j){
    int r = wv*4 + j;
    float v = xl[r*68 + lane];
    float s = v*v;
    for (int o=32;o;o>>=1) s += __shfl_xor(s, o, 64);
    if (lane == 0){
      int rg = row0 + r;
      ws[WS_SQ + rg] = s;
      ws[WS_INV + rg] = 1.0f / fmaxf(sqrtf(s), 1e-12f);
    }
  }
  #pragma unroll
  for (int j=0;j<4;++j){
    int r = wv*4 + j;
    int rg = row0 + r;
    int b = rg >> 11, s_loc = rg & (S_-1);
    float d0 = xl[r*68 + 0], e0 = xl[r*68 + 1];
    float dd = 0.f, de = 0.f, wd = 0.f;
    int n = lane + 1;
    if (lane < NS_ && s_loc >= n){
      const float* xp = x + ((size_t)(b*S_ + s_loc - n))*F_;
      float dp_ = xp[0], ep = xp[1];
      dd = dp_ - d0;
      de = ep - e0;
      wd = scale_w[lane] * __expf(-fabsf(dd) * (1.0f/(float)(1<<n)));
    }
    for (int o=4;o;o>>=1){
      dd += __shfl_down(dd, o, 64);
      de += __shfl_down(de, o, 64);
      wd += __shfl_down(wd, o, 64);
    }
    if (lane == 0){
      ws[WS_REL + rg*3+0] = dd;
      ws[WS_REL + rg*3+1] = de;
      ws[WS_REL + rg*3+2] = wd;
    }
  }
}

// K2: euclid global stats: sum, sumsq (double atomics), raw min/max (uint atomics)
__global__ __launch_bounds__(256) void k2_stats(const float* __restrict__ x, float* __restrict__ ws)
{
  __shared__ __align__(16) float xt[4096];
  __shared__ __align__(16) float xs[64*68];
  __shared__ float sqs[64];
  __shared__ float rsum[4], rss[4], rmn[4], rmx[4];
  int tid = threadIdx.x, lane = tid & 63, wv = tid >> 6;
  int b = blockIdx.z;
  int s0 = blockIdx.x*64, t0 = blockIdx.y*64;
  const float* xb = x + (size_t)b*S_*F_;
  for (int i=0;i<4;++i){
    int idx = tid + i*256; int t = idx>>4, c = idx&15;
    float4 v = *(const float4*)(xb + (size_t)(t0+t)*F_ + c*4);
    int pb = swz_phys(t, c);
    xt[pb]=v.x; xt[pb+1]=v.y; xt[pb+2]=v.z; xt[pb+3]=v.w;
  }
  for (int i=0;i<4;++i){
    int idx = tid + i*256; int r = idx>>4, c = idx&15;
    *(float4*)(xs + r*68 + c*4) = *(const float4*)(xb + (size_t)(s0+r)*F_ + c*4);
  }
  if (tid < 64) sqs[tid] = ws[WS_SQ + b*S_ + s0 + tid];
  __syncthreads();
  float sqt = ws[WS_SQ + b*S_ + t0 + lane];
  float dot[16];
  #pragma unroll
  for (int r=0;r<16;++r) dot[r] = 0.f;
  int swl = lane & 15;
  #pragma unroll
  for (int c=0;c<16;++c){
    float4 tv = *(const float4*)(xt + lane*64 + ((c ^ swl)<<2));
    #pragma unroll
    for (int r=0;r<16;++r){
      float4 sv = *(const float4*)(xs + (wv*16+r)*68 + c*4);
      dot[r] += sv.x*tv.x + sv.y*tv.y + sv.z*tv.z + sv.w*tv.w;
    }
  }
  float lsum=0.f, lss=0.f, lmn=3.4e38f, lmx=-3.4e38f;
  #pragma unroll
  for (int r=0;r<16;++r){
    float d2 = sqs[wv*16+r] + sqt - 2.f*dot[r];
    d2 = fmaxf(d2, 0.f);
    float eu = d2 > 0.f ? sqrtf(d2) : 0.f;
    lsum += eu; lss += eu*eu;
    lmn = fminf(lmn, eu); lmx = fmaxf(lmx, eu);
  }
  for (int o=32;o;o>>=1){
    lsum += __shfl_xor(lsum, o, 64);
    lss  += __shfl_xor(lss, o, 64);
    lmn = fminf(lmn, __shfl_xor(lmn, o, 64));
    lmx = fmaxf(lmx, __shfl_xor(lmx, o, 64));
  }
  if (lane == 0){ rsum[wv]=lsum; rss[wv]=lss; rmn[wv]=lmn; rmx[wv]=lmx; }
  __syncthreads();
  if (tid == 0){
    float bs=0.f, bss=0.f, bmn=3.4e38f, bmx=-3.4e38f;
    for (int w2=0;w2<4;++w2){ bs+=rsum[w2]; bss+=rss[w2]; bmn=fminf(bmn,rmn[w2]); bmx=fmaxf(bmx,rmx[w2]); }
    double* dp = (double*)(ws + WS_STATS);
    atomicAdd(dp,   (double)bs);
    atomicAdd(dp+1, (double)bss);
    unsigned* up = (unsigned*)(ws + WS_STATS + 4);
    atomicMin(up,   fmap_(bmn));
    atomicMax(up+1, fmap_(bmx));
  }
}

// K3: finalize scalars
__global__ void k3_fin(const float* __restrict__ alpha, const float* __restrict__ sigma_w, float* ws){
  double* dp = (double*)(ws + WS_STATS);
  unsigned* up = (unsigned*)(ws + WS_STATS + 4);
  double N = (double)B_*S_*S_;
  double mean = dp[0]/N;
  double var  = (dp[1] - dp[0]*dp[0]/N) / (N - 1.0);
  float stdv = (float)sqrt(fmax(var, 0.0));
  float m = (float)mean;
  float lo = m - 2.f*stdv, hi = m + 2.f*stdv;
  float rmn = funmap_(up[0]), rmx = funmap_(up[1]);
  float cmn = fminf(fmaxf(rmn, lo), hi);
  float cmx = fminf(fmaxf(rmx, lo), hi);
  float invr = 1.f/(cmx - cmn + 1e-6f);
  float a = 1.f/(1.f + expf(-alpha[0]));
  float swv = sigma_w[0];
  float sp = (swv > 20.f) ? swv : log1pf(expf(swv));
  float sg = sp + 0.001f;
  float efac = -0.5f/(sg*sg);
  float* p = ws + WS_STATS + 8;
  p[0]=lo; p[1]=hi; p[2]=cmn; p[3]=invr; p[4]=a; p[5]=1.f-a; p[6]=efac;
}

// K4: flash pass. wave = 4 s-rows; lane = t for scores/G; lane = f for accumulation.
__global__ __launch_bounds__(256) void k4_flash(const float* __restrict__ x, float* __restrict__ ws)
{
  __shared__ __align__(16) float kl[4096];
  __shared__ __align__(16) float xl[4096];
  __shared__ __align__(16) float ql[16*68];
  __shared__ __align__(16) float xsl[16*68];
  __shared__ __align__(16) float el[16*64];
  __shared__ float sqsl[16], invsl[16];
  int tid = threadIdx.x, lane = tid & 63, wv = tid >> 6;
  int b = blockIdx.y;
  int s0 = blockIdx.x * 16;
  size_t rb = (size_t)b * S_;
  const float* xb = x + rb*F_;
  {
    int r = tid >> 4, c = tid & 15;
    *(float4*)(ql  + r*68 + c*4) = *(const float4*)(ws + WS_Q + (rb + s0 + r)*F_ + c*4);
    *(float4*)(xsl + r*68 + c*4) = *(const float4*)(xb + (size_t)(s0+r)*F_ + c*4);
  }
  if (tid < 16){
    sqsl[tid]  = ws[WS_SQ  + rb + s0 + tid];
    invsl[tid] = ws[WS_INV + rb + s0 + tid];
  }
  const float* prm = ws + WS_STATS + 8;
  float lo=prm[0], hi=prm[1], cmn=prm[2], invr=prm[3], a=prm[4], oma=prm[5], efac=prm[6];
  float acc[4], mrun[4], zrun[4];
  #pragma unroll
  for (int j=0;j<4;++j){ acc[j]=0.f; mrun[j]=-3.4e38f; zrun[j]=0.f; }
  __syncthreads();
  float sq_s[4], inv_s[4];
  #pragma unroll
  for (int j=0;j<4;++j){ sq_s[j]=sqsl[wv*4+j]; inv_s[j]=invsl[wv*4+j]; }
  int swl = lane & 15, l4 = lane >> 2, lm = lane & 3;

  for (int t0 = 0; t0 < S_; t0 += 64){
    // stage k and x tiles (swizzled rows)
    for (int i=0;i<4;++i){
      int idx = tid + i*256; int t = idx>>4, c = idx&15;
      int pb = swz_phys(t, c);
      float4 v = *(const float4*)(ws + WS_K + (rb + t0 + t)*F_ + c*4);
      kl[pb]=v.x; kl[pb+1]=v.y; kl[pb+2]=v.z; kl[pb+3]=v.w;
      float4 u = *(const float4*)(xb + (size_t)(t0+t)*F_ + c*4);
      xl[pb]=u.x; xl[pb+1]=u.y; xl[pb+2]=u.z; xl[pb+3]=u.w;
    }
    float sqt  = ws[WS_SQ  + rb + t0 + lane];
    float invt = ws[WS_INV + rb + t0 + lane];
    __syncthreads();
    // scores + gram, 4 rows
    float sc[4], gg[4];
    #pragma unroll
    for (int j=0;j<4;++j){ sc[j]=0.f; gg[j]=0.f; }
    #pragma unroll
    for (int c=0;c<16;++c){
      float4 kv = *(const float4*)(kl + lane*64 + ((c ^ swl)<<2));
      float4 xv = *(const float4*)(xl + lane*64 + ((c ^ swl)<<2));
      #pragma unroll
      for (int j=0;j<4;++j){
        float4 qv = *(const float4*)(ql  + (wv*4+j)*68 + c*4);
        float4 sv = *(const float4*)(xsl + (wv*4+j)*68 + c*4);
        sc[j] += qv.x*kv.x + qv.y*kv.y + qv.z*kv.z + qv.w*kv.w;
        gg[j] += sv.x*xv.x + sv.y*xv.y + sv.z*xv.z + sv.w*xv.w;
      }
    }
    #pragma unroll
    for (int j=0;j<4;++j){
      float score = sc[j] * 0.125f;
      float cosv = (gg[j]*inv_s[j]*invt + 1.f)*0.5f;
      float d2 = sq_s[j] + sqt - 2.f*gg[j];
      d2 = fmaxf(d2, 0.f);
      float eu = d2 > 0.f ? sqrtf(d2) : 0.f;
      eu = fminf(fmaxf(eu, lo), hi);
      float en = (eu - cmn)*invr;
      float hyb = a*cosv + oma*(1.f - en);
      float H = __expf(hyb*efac);
      float tm = score;
      for (int o=32;o;o>>=1) tm = fmaxf(tm, __shfl_xor(tm, o, 64));
      float mnew = fmaxf(mrun[j], tm);
      float scl = __expf(mrun[j] - mnew);
      acc[j] *= scl; zrun[j] *= scl; mrun[j] = mnew;
      float p = __expf(score - mnew);
      zrun[j] += p;
      el[(wv*4+j)*64 + lane] = p * H;
    }
    __syncthreads();   // el visible / all waves done before acc reads + next restage
    // accumulate: acc[j] (f = lane) += sum_t e[j][t] * x[t][lane]
    #pragma unroll
    for (int ji=0; ji<16; ++ji){
      float4 e0 = *(const float4*)(el + (wv*4+0)*64 + ji*4);
      float4 e1 = *(const float4*)(el + (wv*4+1)*64 + ji*4);
      float4 e2 = *(const float4*)(el + (wv*4+2)*64 + ji*4);
      float4 e3 = *(const float4*)(el + (wv*4+3)*64 + ji*4);
      #pragma unroll
      for (int jo=0; jo<4; ++jo){
        int t = ji*4 + jo;
        float xcol = xl[t*64 + ((l4 ^ (t & 15))<<2) + lm];
        acc[0] += COMP(e0,jo) * xcol;
        acc[1] += COMP(e1,jo) * xcol;
        acc[2] += COMP(e2,jo) * xcol;
        acc[3] += COMP(e3,jo) * xcol;
      }
    }
    __syncthreads();
  }
  #pragma unroll
  for (int j=0;j<4;++j){
    float z = zrun[j];
    for (int o=32;o;o>>=1) z += __shfl_xor(z, o, 64);
    ws[WS_PE + (rb + s0 + wv*4+j)*F_ + lane] = acc[j] / z;
  }
}

// K5: pe_proj = pe_event@w_proj^T + b_proj, LN(g2,bt2); rel_enc from rel_sum, LN(g1,bt1); add.
__global__ __launch_bounds__(256) void k5_final(
    const float* __restrict__ w_rel, const float* __restrict__ b_rel,
    const float* __restrict__ w_proj, const float* __restrict__ b_proj,
    const float* __restrict__ g1, const float* __restrict__ bt1,
    const float* __restrict__ g2, const float* __restrict__ bt2,
    const float* __restrict__ ws, float* __restrict__ out)
{
  __shared__ __align__(16) float pel[16*68];
  __shared__ __align__(16) float wpl[4096];
  __shared__ __align__(16) float res[16*512];
  __shared__ float rsl[48];
  __shared__ float g1l[512], b1l[512], g2l[512], b2l[512], brl[512], wrl[1536];
  int tid = threadIdx.x, lane = tid & 63, wv = tid >> 6;
  int row0 = blockIdx.x * 16;
  {
    int r = tid >> 4, c = tid & 15;
    *(float4*)(pel + r*68 + c*4) = *(const float4*)(ws + WS_PE + (size_t)(row0+r)*F_ + c*4);
  }
  if (tid < 48) rsl[tid] = ws[WS_REL + row0*3 + tid];
  for (int i = tid; i < 512; i += 256){
    g1l[i]=g1[i]; b1l[i]=bt1[i]; g2l[i]=g2[i]; b2l[i]=bt2[i]; brl[i]=b_rel[i];
  }
  for (int i = tid; i < 1536; i += 256) wrl[i] = w_rel[i];
  for (int ch = 0; ch < 8; ++ch){
    __syncthreads();
    for (int i=0;i<4;++i){
      int idx = tid + i*256; int d = idx>>4, c = idx&15;
      float4 v = *(const float4*)(w_proj + (size_t)(ch*64+d)*F_ + c*4);
      int pb = swz_phys(d, c);
      wpl[pb]=v.x; wpl[pb+1]=v.y; wpl[pb+2]=v.z; wpl[pb+3]=v.w;
    }
    __syncthreads();
    int d = ch*64 + lane;
    float bp = b_proj[d];
    float ac[4];
    #pragma unroll
    for (int j=0;j<4;++j) ac[j] = bp;
    int swl = lane & 15;
    #pragma unroll
    for (int c=0;c<16;++c){
      float4 wv4 = *(const float4*)(wpl + lane*64 + ((c ^ swl)<<2));
      #pragma unroll
      for (int j=0;j<4;++j){
        float4 pv = *(const float4*)(pel + (wv*4+j)*68 + c*4);
        ac[j] += pv.x*wv4.x + pv.y*wv4.y + pv.z*wv4.z + pv.w*wv4.w;
      }
    }
    #pragma unroll
    for (int j=0;j<4;++j) res[(wv*4+j)*512 + d] = ac[j];
  }
  __syncthreads();
  #pragma unroll
  for (int j=0;j<4;++j){
    int r = wv*4 + j;
    int rg = row0 + r;
    float s1=0.f, q1=0.f;
    float vals[8];
    #pragma unroll
    for (int i=0;i<8;++i){ float v = res[r*512 + i*64 + lane]; vals[i]=v; s1+=v; q1+=v*v; }
    for (int o=32;o;o>>=1){ s1 += __shfl_xor(s1,o,64); q1 += __shfl_xor(q1,o,64); }
    float mu1 = s1*(1.f/512.f);
    float var1 = q1*(1.f/512.f) - mu1*mu1;
    float rsg1 = rsqrtf(fmaxf(var1, 0.f) + 1e-5f);
    float c0 = rsl[r*3+0], c1 = rsl[r*3+1], c2 = rsl[r*3+2];
    float rv[8]; float s2=0.f, q2=0.f;
    #pragma unroll
    for (int i=0;i<8;++i){
      int d = i*64 + lane;
      float v = c0*wrl[d*3+0] + c1*wrl[d*3+1] + c2*wrl[d*3+2] + 5.f*brl[d];
      rv[i]=v; s2+=v; q2+=v*v;
    }
    for (int o=32;o;o>>=1){ s2 += __shfl_xor(s2,o,64); q2 += __shfl_xor(q2,o,64); }
    float mu2 = s2*(1.f/512.f);
    float var2 = q2*(1.f/512.f) - mu2*mu2;
    float rsg2 = rsqrtf(fmaxf(var2, 0.f) + 1e-5f);
    #pragma unroll
    for (int i=0;i<8;++i){
      int d = i*64 + lane;
      float o1 = (vals[i]-mu1)*rsg1*g2l[d] + b2l[d];
      float o2 = (rv[i]-mu2)*rsg2*g1l[d] + b1l[d];
      out[(size_t)rg*512 + d] = o1 + o2;
    }
  }
}

extern "C" void kernel_launch(void* const* d_in, const int* in_sizes, int n_in,
                              void* d_out, int out_size, void* d_ws, size_t ws_size,
                              hipStream_t stream)
{
  const float* x      = (const float*)d_in[0];
  const float* w_rel  = (const float*)d_in[1];
  const float* b_rel  = (const float*)d_in[2];
  const float* w_proj = (const float*)d_in[3];
  const float* b_proj = (const float*)d_in[4];
  const float* g1     = (const float*)d_in[5];
  const float* bt1    = (const float*)d_in[6];
  const float* g2     = (const float*)d_in[7];
  const float* bt2    = (const float*)d_in[8];
  const float* alpha  = (const float*)d_in[9];
  const float* sigma_w= (const float*)d_in[10];
  const float* wq     = (const float*)d_in[11];
  const float* bq     = (const float*)d_in[12];
  const float* wk     = (const float*)d_in[13];
  const float* bk     = (const float*)d_in[14];
  const float* scale_w= (const float*)d_in[15];
  float* wsf = (float*)d_ws;
  float* out = (float*)d_out;

  hipLaunchKernelGGL(k0_init, dim3(1), dim3(1), 0, stream, wsf);
  hipLaunchKernelGGL(k1_prep, dim3(BS_/16), dim3(256), 0, stream, x, wq, bq, wk, bk, scale_w, wsf);
  hipLaunchKernelGGL(k2_stats, dim3(S_/64, S_/64, B_), dim3(256), 0, stream, x, wsf);
  hipLaunchKernelGGL(k3_fin, dim3(1), dim3(1), 0, stream, alpha, sigma_w, wsf);
  hipLaunchKernelGGL(k4_flash, dim3(S_/16, B_), dim3(256), 0, stream, x, wsf);
  hipLaunchKernelGGL(k5_final, dim3(BS_/16), dim3(256), 0, stream,
                     w_rel, b_rel, w_proj, b_proj, g1, bt1, g2, bt2, wsf, out);
}

// Round 2
// 477.998 us; speedup vs baseline: 2.5040x; 2.5040x over previous
//
#include <hip/hip_runtime.h>
#include <math.h>

#define B_ 8
#define S_ 2048
#define F_ 64
#define D_ 512
#define NS_ 5
#define BS_ (B_*S_)

typedef unsigned short u16;
typedef __attribute__((ext_vector_type(8))) short short8;
typedef __attribute__((ext_vector_type(4))) float f32x4;

// float-region offsets (in floats)
#define WS_SQ    0
#define WS_REL   (BS_)
#define WS_PE    (4*BS_)
#define WS_STATS (68*BS_)
#define US_BASE_FLOATS (68*BS_ + 16)
// ushort-region offsets (in ushorts, from usb)
#define US_XB 0
#define US_QB (BS_*64)
#define US_KB (2*BS_*64)
#define US_XT (3*BS_*64)

#define MFMA16(a,b,c) __builtin_amdgcn_mfma_f32_16x16x32_bf16(a,b,c,0,0,0)

__device__ __forceinline__ u16 f2bf(float f){
  unsigned u = __float_as_uint(f);
  return (u16)((u + 0x7FFFu + ((u>>16)&1u)) >> 16);
}
__device__ __forceinline__ unsigned fmap_(float f){
  unsigned u = __float_as_uint(f);
  return (u & 0x80000000u) ? ~u : (u | 0x80000000u);
}
__device__ __forceinline__ float funmap_(unsigned u){
  return (u & 0x80000000u) ? __uint_as_float(u ^ 0x80000000u) : __uint_as_float(~u);
}
// f32-tile swizzle used by k1/k5 (unchanged from passing round-1)
__device__ __forceinline__ int swz_phys(int row, int c){ return row*64 + (((c ^ (row & 15))) << 2); }

__global__ void k0_init(float* ws){
  double* dp = (double*)(ws + WS_STATS);
  dp[0] = 0.0; dp[1] = 0.0;
  unsigned* up = (unsigned*)(ws + WS_STATS + 4);
  up[0] = 0xFFFFFFFFu; up[1] = 0u;
}

// K1: q/k (fp32 compute -> bf16 store), sq, rel sums, xb16, xT16
__global__ __launch_bounds__(256) void k1_prep(
    const float* __restrict__ x, const float* __restrict__ wq, const float* __restrict__ bq,
    const float* __restrict__ wk, const float* __restrict__ bk,
    const float* __restrict__ scale_w, float* __restrict__ ws, u16* __restrict__ usb)
{
  __shared__ __align__(16) float xl[16*68];
  __shared__ __align__(16) float wql[4096];
  __shared__ __align__(16) float wkl[4096];
  int tid = threadIdx.x, lane = tid & 63, wv = tid >> 6;
  int row0 = blockIdx.x * 16;
  {
    int r = tid >> 4, c = tid & 15;
    *(float4*)(xl + r*68 + c*4) = *(const float4*)(x + (size_t)(row0 + r)*F_ + c*4);
  }
  for (int i = 0; i < 4; ++i){
    int idx = tid + i*256;
    int g = idx >> 4, c = idx & 15;
    float4 v = *(const float4*)(wq + g*F_ + c*4);
    int pb = swz_phys(g, c);
    wql[pb]=v.x; wql[pb+1]=v.y; wql[pb+2]=v.z; wql[pb+3]=v.w;
    float4 u = *(const float4*)(wk + g*F_ + c*4);
    wkl[pb]=u.x; wkl[pb+1]=u.y; wkl[pb+2]=u.z; wkl[pb+3]=u.w;
  }
  __syncthreads();
  int g = lane;
  int swl = g & 15;
  float qa[4], ka[4];
  #pragma unroll
  for (int j=0;j<4;++j){ qa[j]=bq[g]; ka[j]=bk[g]; }
  #pragma unroll
  for (int c=0;c<16;++c){
    float4 wqv = *(const float4*)(wql + g*64 + ((c ^ swl)<<2));
    float4 wkv = *(const float4*)(wkl + g*64 + ((c ^ swl)<<2));
    #pragma unroll
    for (int j=0;j<4;++j){
      float4 xv = *(const float4*)(xl + (wv*4+j)*68 + c*4);
      qa[j] += xv.x*wqv.x + xv.y*wqv.y + xv.z*wqv.z + xv.w*wqv.w;
      ka[j] += xv.x*wkv.x + xv.y*wkv.y + xv.z*wkv.z + xv.w*wkv.w;
    }
  }
  #pragma unroll
  for (int j=0;j<4;++j){
    int rg = row0 + wv*4 + j;
    usb[US_QB + (size_t)rg*64 + g] = f2bf(qa[j]);
    usb[US_KB + (size_t)rg*64 + g] = f2bf(ka[j]);
  }
  #pragma unroll
  for (int j=0;j<4;++j){
    int r = wv*4 + j;
    float v = xl[r*68 + lane];
    float s = v*v;
    for (int o=32;o;o>>=1) s += __shfl_xor(s, o, 64);
    if (lane == 0) ws[WS_SQ + row0 + r] = s;
  }
  #pragma unroll
  for (int j=0;j<4;++j){
    int r = wv*4 + j;
    int rg = row0 + r;
    int b = rg >> 11, s_loc = rg & (S_-1);
    float d0 = xl[r*68 + 0], e0 = xl[r*68 + 1];
    float dd = 0.f, de = 0.f, wd = 0.f;
    int n = lane + 1;
    if (lane < NS_ && s_loc >= n){
      const float* xp = x + ((size_t)(b*S_ + s_loc - n))*F_;
      float dp_ = xp[0], ep = xp[1];
      dd = dp_ - d0;
      de = ep - e0;
      wd = scale_w[lane] * __expf(-fabsf(dd) * (1.0f/(float)(1<<n)));
    }
    for (int o=4;o;o>>=1){
      dd += __shfl_down(dd, o, 64);
      de += __shfl_down(de, o, 64);
      wd += __shfl_down(wd, o, 64);
    }
    if (lane == 0){
      ws[WS_REL + rg*3+0] = dd;
      ws[WS_REL + rg*3+1] = de;
      ws[WS_REL + rg*3+2] = wd;
    }
  }
  // bf16 x (row-major)
  {
    int r = tid >> 4, cb = (tid & 15)*4;
    unsigned w0 = (unsigned)f2bf(xl[r*68+cb])   | ((unsigned)f2bf(xl[r*68+cb+1])<<16);
    unsigned w1 = (unsigned)f2bf(xl[r*68+cb+2]) | ((unsigned)f2bf(xl[r*68+cb+3])<<16);
    uint2 pk; pk.x = w0; pk.y = w1;
    *(uint2*)(usb + US_XB + (size_t)(row0+r)*64 + cb) = pk;
  }
  // bf16 x transposed per batch: xT[b][f][t]
  {
    int f = tid & 63, rg4 = (tid >> 6)*4;
    unsigned wa = (unsigned)f2bf(xl[(rg4+0)*68+f]) | ((unsigned)f2bf(xl[(rg4+1)*68+f])<<16);
    unsigned wb = (unsigned)f2bf(xl[(rg4+2)*68+f]) | ((unsigned)f2bf(xl[(rg4+3)*68+f])<<16);
    uint2 pk; pk.x = wa; pk.y = wb;
    int bb = row0 >> 11;
    int tloc = (row0 & (S_-1)) + rg4;
    *(uint2*)(usb + US_XT + (size_t)bb*64*2048 + (size_t)f*2048 + tloc) = pk;
  }
}

// K2: euclid stats via MFMA Gram, upper-triangle tiles only (off-diag weight 2)
__global__ __launch_bounds__(256) void k2_stats(const u16* __restrict__ us, float* __restrict__ ws)
{
  __shared__ __align__(16) u16 Xls[4096];
  __shared__ float sqs_l[64], sqt_l[64];
  __shared__ float rsum[4], rss[4], rmn[4], rmx[4];
  int tid = threadIdx.x, lane = tid & 63, wv = tid >> 6;
  int lg = lane >> 4, lc = lane & 15;
  int b = blockIdx.y;
  int rem = blockIdx.x, i = 0;
  while (rem >= 32 - i){ rem -= 32 - i; ++i; }
  int j = i + rem;
  int s0 = i*64, t0 = j*64;
  size_t rb = (size_t)b * S_;
  const u16* xb = us + US_XB;
  #pragma unroll
  for (int p2=0;p2<2;++p2){
    int slot = tid + p2*256;
    int row = slot>>3, pc = slot&7, lcn = pc ^ (row&7);
    ((short8*)Xls)[slot] = *(const short8*)(xb + (rb + t0 + row)*64 + lcn*8);
  }
  if (tid < 64) sqs_l[tid] = ws[WS_SQ + rb + s0 + tid];
  else if (tid < 128) sqt_l[tid-64] = ws[WS_SQ + rb + t0 + (tid-64)];
  short8 a0 = *(const short8*)(xb + (rb + s0 + wv*16 + lc)*64 + lg*8);
  short8 a1 = *(const short8*)(xb + (rb + s0 + wv*16 + lc)*64 + 32 + lg*8);
  __syncthreads();
  f32x4 acc[4];
  #pragma unroll
  for (int t=0;t<4;++t){ acc[t][0]=0.f; acc[t][1]=0.f; acc[t][2]=0.f; acc[t][3]=0.f; }
  #pragma unroll
  for (int ts=0; ts<4; ++ts){
    int rowb = ts*16 + lc;
    int sw = rowb & 7;
    short8 b0 = *(const short8*)(Xls + rowb*64 + ((lg ^ sw)<<3));
    short8 b1 = *(const short8*)(Xls + rowb*64 + (((4+lg) ^ sw)<<3));
    acc[ts] = MFMA16(a0, b0, acc[ts]);
    acc[ts] = MFMA16(a1, b1, acc[ts]);
  }
  float sq_s[4];
  #pragma unroll
  for (int r=0;r<4;++r) sq_s[r] = sqs_l[wv*16 + lg*4 + r];
  float lsum=0.f, lss=0.f, lmn=3.4e38f, lmx=-3.4e38f;
  #pragma unroll
  for (int ts=0; ts<4; ++ts){
    float sqt = sqt_l[ts*16 + lc];
    #pragma unroll
    for (int r=0;r<4;++r){
      float gg = acc[ts][r];
      float d2 = sq_s[r] + sqt - 2.f*gg;
      d2 = fmaxf(d2, 0.f);
      float eu = d2 > 0.f ? sqrtf(d2) : 0.f;
      lsum += eu; lss += eu*eu;
      lmn = fminf(lmn, eu); lmx = fmaxf(lmx, eu);
    }
  }
  for (int o=32;o;o>>=1){
    lsum += __shfl_xor(lsum, o, 64);
    lss  += __shfl_xor(lss, o, 64);
    lmn = fminf(lmn, __shfl_xor(lmn, o, 64));
    lmx = fmaxf(lmx, __shfl_xor(lmx, o, 64));
  }
  if (lane == 0){ rsum[wv]=lsum; rss[wv]=lss; rmn[wv]=lmn; rmx[wv]=lmx; }
  __syncthreads();
  if (tid == 0){
    float bs=0.f, bss=0.f, bmn=3.4e38f, bmx=-3.4e38f;
    for (int w2=0;w2<4;++w2){ bs+=rsum[w2]; bss+=rss[w2]; bmn=fminf(bmn,rmn[w2]); bmx=fmaxf(bmx,rmx[w2]); }
    float wgt = (i==j) ? 1.f : 2.f;
    double* dp = (double*)(ws + WS_STATS);
    atomicAdd(dp,   (double)(bs*wgt));
    atomicAdd(dp+1, (double)(bss*wgt));
    unsigned* up = (unsigned*)(ws + WS_STATS + 4);
    atomicMin(up,   fmap_(bmn));
    atomicMax(up+1, fmap_(bmx));
  }
}

__global__ void k3_fin(const float* __restrict__ alpha, const float* __restrict__ sigma_w, float* ws){
  double* dp = (double*)(ws + WS_STATS);
  unsigned* up = (unsigned*)(ws + WS_STATS + 4);
  double N = (double)B_*S_*S_;
  double mean = dp[0]/N;
  double var  = (dp[1] - dp[0]*dp[0]/N) / (N - 1.0);
  float stdv = (float)sqrt(fmax(var, 0.0));
  float m = (float)mean;
  float lo = m - 2.f*stdv, hi = m + 2.f*stdv;
  float rmn = funmap_(up[0]), rmx = funmap_(up[1]);
  float cmn = fminf(fmaxf(rmn, lo), hi);
  float cmx = fminf(fmaxf(rmx, lo), hi);
  float invr = 1.f/(cmx - cmn + 1e-6f);
  float a = 1.f/(1.f + expf(-alpha[0]));
  float swv = sigma_w[0];
  float sp = (swv > 20.f) ? swv : log1pf(expf(swv));
  float sg = sp + 0.001f;
  float efac = -0.5f/(sg*sg);
  float* p = ws + WS_STATS + 8;
  p[0]=lo; p[1]=hi; p[2]=cmn; p[3]=invr; p[4]=a; p[5]=1.f-a; p[6]=efac;
}

// K4: MFMA flash pass. 8 waves: (ssub 0..3) x (t-half 0..1). s-tile 64, t-tile 64.
__global__ __launch_bounds__(512) void k4_flash(const u16* __restrict__ us, float* __restrict__ ws)
{
  __shared__ __align__(16) u16 SMEM[16384];  // Kls|Xls|XTls|el : 4x8KB
  __shared__ float sqt_l[64], invt_l[64];
  __shared__ float rmx_l[4][2][16];
  __shared__ float zb[4][2][16];
  u16* Kls  = SMEM;
  u16* Xls  = SMEM + 4096;
  u16* XTls = SMEM + 8192;
  u16* elp  = SMEM + 12288;
  int tid = threadIdx.x, lane = tid & 63, wv = tid >> 6;
  int lg = lane >> 4, lc = lane & 15;
  int ssub = wv >> 1, th = wv & 1;
  int b = blockIdx.y;
  size_t rb = (size_t)b * S_;
  int s0 = blockIdx.x * 64;
  const u16* xb = us + US_XB;
  const u16* qb = us + US_QB;
  const u16* kb = us + US_KB;
  const u16* xt = us + US_XT + (size_t)b*64*2048;
  int srow = s0 + ssub*16 + lc;
  short8 qf0 = *(const short8*)(qb + (rb+srow)*64 + lg*8);
  short8 qf1 = *(const short8*)(qb + (rb+srow)*64 + 32 + lg*8);
  short8 xf0 = *(const short8*)(xb + (rb+srow)*64 + lg*8);
  short8 xf1 = *(const short8*)(xb + (rb+srow)*64 + 32 + lg*8);
  float sq_s[4], inv_s[4];
  #pragma unroll
  for (int r=0;r<4;++r){
    float s = ws[WS_SQ + rb + s0 + ssub*16 + lg*4 + r];
    sq_s[r] = s; inv_s[r] = 1.f / fmaxf(sqrtf(s), 1e-12f);
  }
  const float* prm = ws + WS_STATS + 8;
  float lo=prm[0], hi=prm[1], cmn=prm[2], invr=prm[3], a=prm[4], oma=prm[5], efac=prm[6];
  f32x4 pe[4];
  #pragma unroll
  for (int t=0;t<4;++t){ pe[t][0]=0.f; pe[t][1]=0.f; pe[t][2]=0.f; pe[t][3]=0.f; }
  float mrun[4], zrun[4];
  #pragma unroll
  for (int r=0;r<4;++r){ mrun[r]=-3.4e38f; zrun[r]=0.f; }

  for (int t0 = 0; t0 < S_; t0 += 64){
    {
      int slot = tid;
      int row = slot>>3, pc = slot&7, lcn = pc ^ (row&7);
      ((short8*)Kls)[slot]  = *(const short8*)(kb + (rb + t0 + row)*64 + lcn*8);
      ((short8*)Xls)[slot]  = *(const short8*)(xb + (rb + t0 + row)*64 + lcn*8);
      ((short8*)XTls)[slot] = *(const short8*)(xt + (size_t)row*2048 + t0 + lcn*8);
    }
    if (tid < 64){
      float s = ws[WS_SQ + rb + t0 + tid];
      sqt_l[tid] = s;
      invt_l[tid] = 1.f / fmaxf(sqrtf(s), 1e-12f);
    }
    __syncthreads();
    f32x4 ga[2], sa[2];
    #pragma unroll
    for (int t=0;t<2;++t){ ga[t][0]=0.f; ga[t][1]=0.f; ga[t][2]=0.f; ga[t][3]=0.f;
                           sa[t][0]=0.f; sa[t][1]=0.f; sa[t][2]=0.f; sa[t][3]=0.f; }
    #pragma unroll
    for (int ts=0; ts<2; ++ts){
      int rowb = (2*th+ts)*16 + lc;
      int sw = rowb & 7;
      short8 bk0 = *(const short8*)(Kls + rowb*64 + ((lg ^ sw)<<3));
      short8 bx0 = *(const short8*)(Xls + rowb*64 + ((lg ^ sw)<<3));
      sa[ts] = MFMA16(qf0, bk0, sa[ts]);
      ga[ts] = MFMA16(xf0, bx0, ga[ts]);
      short8 bk1 = *(const short8*)(Kls + rowb*64 + (((4+lg) ^ sw)<<3));
      short8 bx1 = *(const short8*)(Xls + rowb*64 + (((4+lg) ^ sw)<<3));
      sa[ts] = MFMA16(qf1, bk1, sa[ts]);
      ga[ts] = MFMA16(xf1, bx1, ga[ts]);
    }
    float sc0[4], sc1[4];
    #pragma unroll
    for (int r=0;r<4;++r){
      sc0[r] = sa[0][r]*0.125f;
      sc1[r] = sa[1][r]*0.125f;
      float m = fmaxf(sc0[r], sc1[r]);
      m = fmaxf(m, __shfl_xor(m, 1, 64));
      m = fmaxf(m, __shfl_xor(m, 2, 64));
      m = fmaxf(m, __shfl_xor(m, 4, 64));
      m = fmaxf(m, __shfl_xor(m, 8, 64));
      if (lc == r) rmx_l[ssub][th][lg*4+r] = m;
    }
    __syncthreads();
    #pragma unroll
    for (int r=0;r<4;++r){
      float tmax = fmaxf(rmx_l[ssub][0][lg*4+r], rmx_l[ssub][1][lg*4+r]);
      float mnew = fmaxf(mrun[r], tmax);
      float scl = __expf(mrun[r] - mnew);
      mrun[r] = mnew;
      zrun[r] *= scl;
      pe[0][r]*=scl; pe[1][r]*=scl; pe[2][r]*=scl; pe[3][r]*=scl;
    }
    #pragma unroll
    for (int ts=0; ts<2; ++ts){
      int col = (2*th+ts)*16 + lc;
      float sqt = sqt_l[col], invt = invt_l[col];
      #pragma unroll
      for (int r=0;r<4;++r){
        float gg = (ts==0) ? ga[0][r] : ga[1][r];
        float cosv = (gg*inv_s[r]*invt + 1.f)*0.5f;
        float d2 = sq_s[r] + sqt - 2.f*gg;
        d2 = fmaxf(d2, 0.f);
        float eu = d2 > 0.f ? sqrtf(d2) : 0.f;
        eu = fminf(fmaxf(eu, lo), hi);
        float en = (eu - cmn)*invr;
        float hyb = a*cosv + oma*(1.f - en);
        float H = __expf(hyb*efac);
        float p = __expf(((ts==0)?sc0[r]:sc1[r]) - mrun[r]);
        zrun[r] += p;
        int rowl = lg*4 + r;
        int phys = rowl*64 + ((((col>>3) ^ (rowl&7)))<<3) + (col&7);
        elp[ssub*1024 + phys] = f2bf(p*H);
      }
    }
    // PV: pe[fs] += E(16x32 window) @ x(32 x 16f)
    {
      int swA = lc & 7;
      short8 Ae = *(const short8*)(elp + ssub*1024 + lc*64 + (((4*th + lg) ^ swA)<<3));
      #pragma unroll
      for (int fs=0; fs<4; ++fs){
        int rowf = fs*16 + lc;
        short8 Bx = *(const short8*)(XTls + rowf*64 + (((4*th + lg) ^ (rowf&7))<<3));
        pe[fs] = MFMA16(Ae, Bx, pe[fs]);
      }
    }
    __syncthreads();
  }
  // z reduce + cross-half combine
  #pragma unroll
  for (int r=0;r<4;++r){
    float z = zrun[r];
    z += __shfl_xor(z, 1, 64);
    z += __shfl_xor(z, 2, 64);
    z += __shfl_xor(z, 4, 64);
    z += __shfl_xor(z, 8, 64);
    if (lc == r) zb[ssub][th][lg*4+r] = z;
  }
  __syncthreads();
  float* tmp = (float*)SMEM;  // 4096 floats scratch (tiles dead now)
  if (th == 1){
    #pragma unroll
    for (int fs=0; fs<4; ++fs)
      #pragma unroll
      for (int r=0;r<4;++r)
        tmp[ssub*1024 + (lg*4+r)*64 + fs*16 + lc] = pe[fs][r];
  }
  __syncthreads();
  if (th == 0){
    float zi[4];
    #pragma unroll
    for (int r=0;r<4;++r) zi[r] = 1.f / (zb[ssub][0][lg*4+r] + zb[ssub][1][lg*4+r]);
    #pragma unroll
    for (int fs=0; fs<4; ++fs)
      #pragma unroll
      for (int r=0;r<4;++r){
        float v = pe[fs][r] + tmp[ssub*1024 + (lg*4+r)*64 + fs*16 + lc];
        ws[WS_PE + (rb + s0 + ssub*16 + lg*4 + r)*64 + fs*16 + lc] = v * zi[r];
      }
  }
}

// K5: pe_proj GEMM + both LayerNorms + add (unchanged structure from passing round)
__global__ __launch_bounds__(256) void k5_final(
    const float* __restrict__ w_rel, const float* __restrict__ b_rel,
    const float* __restrict__ w_proj, const float* __restrict__ b_proj,
    const float* __restrict__ g1, const float* __restrict__ bt1,
    const float* __restrict__ g2, const float* __restrict__ bt2,
    const float* __restrict__ ws, float* __restrict__ out)
{
  __shared__ __align__(16) float pel[16*68];
  __shared__ __align__(16) float wpl[4096];
  __shared__ __align__(16) float res[16*512];
  __shared__ float rsl[48];
  __shared__ float g1l[512], b1l[512], g2l[512], b2l[512], brl[512], wrl[1536];
  int tid = threadIdx.x, lane = tid & 63, wv = tid >> 6;
  int row0 = blockIdx.x * 16;
  {
    int r = tid >> 4, c = tid & 15;
    *(float4*)(pel + r*68 + c*4) = *(const float4*)(ws + WS_PE + (size_t)(row0+r)*F_ + c*4);
  }
  if (tid < 48) rsl[tid] = ws[WS_REL + row0*3 + tid];
  for (int i = tid; i < 512; i += 256){
    g1l[i]=g1[i]; b1l[i]=bt1[i]; g2l[i]=g2[i]; b2l[i]=bt2[i]; brl[i]=b_rel[i];
  }
  for (int i = tid; i < 1536; i += 256) wrl[i] = w_rel[i];
  for (int ch = 0; ch < 8; ++ch){
    __syncthreads();
    for (int i=0;i<4;++i){
      int idx = tid + i*256; int d = idx>>4, c = idx&15;
      float4 v = *(const float4*)(w_proj + (size_t)(ch*64+d)*F_ + c*4);
      int pb = swz_phys(d, c);
      wpl[pb]=v.x; wpl[pb+1]=v.y; wpl[pb+2]=v.z; wpl[pb+3]=v.w;
    }
    __syncthreads();
    int d = ch*64 + lane;
    float bp = b_proj[d];
    float ac[4];
    #pragma unroll
    for (int j=0;j<4;++j) ac[j] = bp;
    int swl = lane & 15;
    #pragma unroll
    for (int c=0;c<16;++c){
      float4 wv4 = *(const float4*)(wpl + lane*64 + ((c ^ swl)<<2));
      #pragma unroll
      for (int j=0;j<4;++j){
        float4 pv = *(const float4*)(pel + (wv*4+j)*68 + c*4);
        ac[j] += pv.x*wv4.x + pv.y*wv4.y + pv.z*wv4.z + pv.w*wv4.w;
      }
    }
    #pragma unroll
    for (int j=0;j<4;++j) res[(wv*4+j)*512 + d] = ac[j];
  }
  __syncthreads();
  #pragma unroll
  for (int j=0;j<4;++j){
    int r = wv*4 + j;
    int rg = row0 + r;
    float s1=0.f, q1=0.f;
    float vals[8];
    #pragma unroll
    for (int i=0;i<8;++i){ float v = res[r*512 + i*64 + lane]; vals[i]=v; s1+=v; q1+=v*v; }
    for (int o=32;o;o>>=1){ s1 += __shfl_xor(s1,o,64); q1 += __shfl_xor(q1,o,64); }
    float mu1 = s1*(1.f/512.f);
    float var1 = q1*(1.f/512.f) - mu1*mu1;
    float rsg1 = rsqrtf(fmaxf(var1, 0.f) + 1e-5f);
    float c0 = rsl[r*3+0], c1 = rsl[r*3+1], c2 = rsl[r*3+2];
    float rv[8]; float s2=0.f, q2=0.f;
    #pragma unroll
    for (int i=0;i<8;++i){
      int d = i*64 + lane;
      float v = c0*wrl[d*3+0] + c1*wrl[d*3+1] + c2*wrl[d*3+2] + 5.f*brl[d];
      rv[i]=v; s2+=v; q2+=v*v;
    }
    for (int o=32;o;o>>=1){ s2 += __shfl_xor(s2,o,64); q2 += __shfl_xor(q2,o,64); }
    float mu2 = s2*(1.f/512.f);
    float var2 = q2*(1.f/512.f) - mu2*mu2;
    float rsg2 = rsqrtf(fmaxf(var2, 0.f) + 1e-5f);
    #pragma unroll
    for (int i=0;i<8;++i){
      int d = i*64 + lane;
      float o1 = (vals[i]-mu1)*rsg1*g2l[d] + b2l[d];
      float o2 = (rv[i]-mu2)*rsg2*g1l[d] + b1l[d];
      out[(size_t)rg*512 + d] = o1 + o2;
    }
  }
}

extern "C" void kernel_launch(void* const* d_in, const int* in_sizes, int n_in,
                              void* d_out, int out_size, void* d_ws, size_t ws_size,
                              hipStream_t stream)
{
  const float* x      = (const float*)d_in[0];
  const float* w_rel  = (const float*)d_in[1];
  const float* b_rel  = (const float*)d_in[2];
  const float* w_proj = (const float*)d_in[3];
  const float* b_proj = (const float*)d_in[4];
  const float* g1     = (const float*)d_in[5];
  const float* bt1    = (const float*)d_in[6];
  const float* g2     = (const float*)d_in[7];
  const float* bt2    = (const float*)d_in[8];
  const float* alpha  = (const float*)d_in[9];
  const float* sigma_w= (const float*)d_in[10];
  const float* wq     = (const float*)d_in[11];
  const float* bq     = (const float*)d_in[12];
  const float* wk     = (const float*)d_in[13];
  const float* bk     = (const float*)d_in[14];
  const float* scale_w= (const float*)d_in[15];
  float* wsf = (float*)d_ws;
  u16*  usb = (u16*)(wsf + US_BASE_FLOATS);
  float* out = (float*)d_out;

  hipLaunchKernelGGL(k0_init, dim3(1), dim3(1), 0, stream, wsf);
  hipLaunchKernelGGL(k1_prep, dim3(BS_/16), dim3(256), 0, stream, x, wq, bq, wk, bk, scale_w, wsf, usb);
  hipLaunchKernelGGL(k2_stats, dim3(528, B_), dim3(256), 0, stream, usb, wsf);
  hipLaunchKernelGGL(k3_fin, dim3(1), dim3(1), 0, stream, alpha, sigma_w, wsf);
  hipLaunchKernelGGL(k4_flash, dim3(S_/64, B_), dim3(512), 0, stream, usb, wsf);
  hipLaunchKernelGGL(k5_final, dim3(BS_/16), dim3(256), 0, stream,
                     w_rel, b_rel, w_proj, b_proj, g1, bt1, g2, bt2, wsf, out);
}

// Round 3
// 294.864 us; speedup vs baseline: 4.0592x; 1.6211x over previous
//
#include <hip/hip_runtime.h>
#include <math.h>

#define B_ 8
#define S_ 2048
#define F_ 64
#define D_ 512
#define NS_ 5
#define BS_ (B_*S_)
#define NTILE_ 528
#define NPART_ (NTILE_*B_)

typedef unsigned short u16;
typedef __attribute__((ext_vector_type(8))) short short8;
typedef __attribute__((ext_vector_type(4))) float f32x4;

// float-region offsets (in floats)
#define WS_SQ    0
#define WS_REL   (BS_)
#define WS_PE    (4*BS_)     // also reused (pre-k4) as k2 partials buffer
#define WS_STATS (68*BS_)
#define US_BASE_FLOATS (68*BS_ + 16)
// ushort-region offsets (in ushorts, from usb)
#define US_XB 0
#define US_QB (BS_*64)
#define US_KB (2*BS_*64)
#define US_XT (3*BS_*64)

#define MFMA16(a,b,c) __builtin_amdgcn_mfma_f32_16x16x32_bf16(a,b,c,0,0,0)

__device__ __forceinline__ u16 f2bf(float f){
  unsigned u = __float_as_uint(f);
  return (u16)((u + 0x7FFFu + ((u>>16)&1u)) >> 16);
}
// f32-tile swizzle used by k1/k5
__device__ __forceinline__ int swz_phys(int row, int c){ return row*64 + (((c ^ (row & 15))) << 2); }

// K1: q/k (fp32 compute -> bf16 store), sq, rel sums, xb16, xT16
__global__ __launch_bounds__(256) void k1_prep(
    const float* __restrict__ x, const float* __restrict__ wq, const float* __restrict__ bq,
    const float* __restrict__ wk, const float* __restrict__ bk,
    const float* __restrict__ scale_w, float* __restrict__ ws, u16* __restrict__ usb)
{
  __shared__ __align__(16) float xl[16*68];
  __shared__ __align__(16) float wql[4096];
  __shared__ __align__(16) float wkl[4096];
  int tid = threadIdx.x, lane = tid & 63, wv = tid >> 6;
  int row0 = blockIdx.x * 16;
  {
    int r = tid >> 4, c = tid & 15;
    *(float4*)(xl + r*68 + c*4) = *(const float4*)(x + (size_t)(row0 + r)*F_ + c*4);
  }
  for (int i = 0; i < 4; ++i){
    int idx = tid + i*256;
    int g = idx >> 4, c = idx & 15;
    float4 v = *(const float4*)(wq + g*F_ + c*4);
    int pb = swz_phys(g, c);
    wql[pb]=v.x; wql[pb+1]=v.y; wql[pb+2]=v.z; wql[pb+3]=v.w;
    float4 u = *(const float4*)(wk + g*F_ + c*4);
    wkl[pb]=u.x; wkl[pb+1]=u.y; wkl[pb+2]=u.z; wkl[pb+3]=u.w;
  }
  __syncthreads();
  int g = lane;
  int swl = g & 15;
  float qa[4], ka[4];
  #pragma unroll
  for (int j=0;j<4;++j){ qa[j]=bq[g]; ka[j]=bk[g]; }
  #pragma unroll
  for (int c=0;c<16;++c){
    float4 wqv = *(const float4*)(wql + g*64 + ((c ^ swl)<<2));
    float4 wkv = *(const float4*)(wkl + g*64 + ((c ^ swl)<<2));
    #pragma unroll
    for (int j=0;j<4;++j){
      float4 xv = *(const float4*)(xl + (wv*4+j)*68 + c*4);
      qa[j] += xv.x*wqv.x + xv.y*wqv.y + xv.z*wqv.z + xv.w*wqv.w;
      ka[j] += xv.x*wkv.x + xv.y*wkv.y + xv.z*wkv.z + xv.w*wkv.w;
    }
  }
  #pragma unroll
  for (int j=0;j<4;++j){
    int rg = row0 + wv*4 + j;
    usb[US_QB + (size_t)rg*64 + g] = f2bf(qa[j]);
    usb[US_KB + (size_t)rg*64 + g] = f2bf(ka[j]);
  }
  #pragma unroll
  for (int j=0;j<4;++j){
    int r = wv*4 + j;
    float v = xl[r*68 + lane];
    float s = v*v;
    for (int o=32;o;o>>=1) s += __shfl_xor(s, o, 64);
    if (lane == 0) ws[WS_SQ + row0 + r] = s;
  }
  #pragma unroll
  for (int j=0;j<4;++j){
    int r = wv*4 + j;
    int rg = row0 + r;
    int b = rg >> 11, s_loc = rg & (S_-1);
    float d0 = xl[r*68 + 0], e0 = xl[r*68 + 1];
    float dd = 0.f, de = 0.f, wd = 0.f;
    int n = lane + 1;
    if (lane < NS_ && s_loc >= n){
      const float* xp = x + ((size_t)(b*S_ + s_loc - n))*F_;
      float dp_ = xp[0], ep = xp[1];
      dd = dp_ - d0;
      de = ep - e0;
      wd = scale_w[lane] * __expf(-fabsf(dd) * (1.0f/(float)(1<<n)));
    }
    for (int o=4;o;o>>=1){
      dd += __shfl_down(dd, o, 64);
      de += __shfl_down(de, o, 64);
      wd += __shfl_down(wd, o, 64);
    }
    if (lane == 0){
      ws[WS_REL + rg*3+0] = dd;
      ws[WS_REL + rg*3+1] = de;
      ws[WS_REL + rg*3+2] = wd;
    }
  }
  // bf16 x (row-major)
  {
    int r = tid >> 4, cb = (tid & 15)*4;
    unsigned w0 = (unsigned)f2bf(xl[r*68+cb])   | ((unsigned)f2bf(xl[r*68+cb+1])<<16);
    unsigned w1 = (unsigned)f2bf(xl[r*68+cb+2]) | ((unsigned)f2bf(xl[r*68+cb+3])<<16);
    uint2 pk; pk.x = w0; pk.y = w1;
    *(uint2*)(usb + US_XB + (size_t)(row0+r)*64 + cb) = pk;
  }
  // bf16 x transposed per batch: xT[b][f][t]
  {
    int f = tid & 63, rg4 = (tid >> 6)*4;
    unsigned wa = (unsigned)f2bf(xl[(rg4+0)*68+f]) | ((unsigned)f2bf(xl[(rg4+1)*68+f])<<16);
    unsigned wb = (unsigned)f2bf(xl[(rg4+2)*68+f]) | ((unsigned)f2bf(xl[(rg4+3)*68+f])<<16);
    uint2 pk; pk.x = wa; pk.y = wb;
    int bb = row0 >> 11;
    int tloc = (row0 & (S_-1)) + rg4;
    *(uint2*)(usb + US_XT + (size_t)bb*64*2048 + (size_t)f*2048 + tloc) = pk;
  }
}

// K2: euclid stats via MFMA Gram, upper-triangle tiles only (off-diag weight 2).
// NO global atomics: per-block partials -> WS_PE region (dead until k4).
__global__ __launch_bounds__(256) void k2_stats(const u16* __restrict__ us, float* __restrict__ ws)
{
  __shared__ __align__(16) u16 Xls[4096];
  __shared__ float sqs_l[64], sqt_l[64];
  __shared__ float rsum[4], rss[4], rmn[4], rmx[4];
  int tid = threadIdx.x, lane = tid & 63, wv = tid >> 6;
  int lg = lane >> 4, lc = lane & 15;
  int b = blockIdx.y;
  int rem = blockIdx.x, i = 0;
  while (rem >= 32 - i){ rem -= 32 - i; ++i; }
  int j = i + rem;
  int s0 = i*64, t0 = j*64;
  size_t rb = (size_t)b * S_;
  const u16* xb = us + US_XB;
  #pragma unroll
  for (int p2=0;p2<2;++p2){
    int slot = tid + p2*256;
    int row = slot>>3, pc = slot&7, lcn = pc ^ (row&7);
    ((short8*)Xls)[slot] = *(const short8*)(xb + (rb + t0 + row)*64 + lcn*8);
  }
  if (tid < 64) sqs_l[tid] = ws[WS_SQ + rb + s0 + tid];
  else if (tid < 128) sqt_l[tid-64] = ws[WS_SQ + rb + t0 + (tid-64)];
  short8 a0 = *(const short8*)(xb + (rb + s0 + wv*16 + lc)*64 + lg*8);
  short8 a1 = *(const short8*)(xb + (rb + s0 + wv*16 + lc)*64 + 32 + lg*8);
  __syncthreads();
  f32x4 acc[4];
  #pragma unroll
  for (int t=0;t<4;++t){ acc[t][0]=0.f; acc[t][1]=0.f; acc[t][2]=0.f; acc[t][3]=0.f; }
  #pragma unroll
  for (int ts=0; ts<4; ++ts){
    int rowb = ts*16 + lc;
    int sw = rowb & 7;
    short8 b0 = *(const short8*)(Xls + rowb*64 + ((lg ^ sw)<<3));
    short8 b1 = *(const short8*)(Xls + rowb*64 + (((4+lg) ^ sw)<<3));
    acc[ts] = MFMA16(a0, b0, acc[ts]);
    acc[ts] = MFMA16(a1, b1, acc[ts]);
  }
  float sq_s[4];
  #pragma unroll
  for (int r=0;r<4;++r) sq_s[r] = sqs_l[wv*16 + lg*4 + r];
  float lsum=0.f, lss=0.f, lmn=3.4e38f, lmx=-3.4e38f;
  #pragma unroll
  for (int ts=0; ts<4; ++ts){
    float sqt = sqt_l[ts*16 + lc];
    #pragma unroll
    for (int r=0;r<4;++r){
      float gg = acc[ts][r];
      float d2 = sq_s[r] + sqt - 2.f*gg;
      d2 = fmaxf(d2, 0.f);
      float eu = d2 > 0.f ? sqrtf(d2) : 0.f;
      lsum += eu; lss += eu*eu;
      lmn = fminf(lmn, eu); lmx = fmaxf(lmx, eu);
    }
  }
  for (int o=32;o;o>>=1){
    lsum += __shfl_xor(lsum, o, 64);
    lss  += __shfl_xor(lss, o, 64);
    lmn = fminf(lmn, __shfl_xor(lmn, o, 64));
    lmx = fmaxf(lmx, __shfl_xor(lmx, o, 64));
  }
  if (lane == 0){ rsum[wv]=lsum; rss[wv]=lss; rmn[wv]=lmn; rmx[wv]=lmx; }
  __syncthreads();
  if (tid == 0){
    float bs=0.f, bss=0.f, bmn=3.4e38f, bmx=-3.4e38f;
    for (int w2=0;w2<4;++w2){ bs+=rsum[w2]; bss+=rss[w2]; bmn=fminf(bmn,rmn[w2]); bmx=fmaxf(bmx,rmx[w2]); }
    float wgt = (i==j) ? 1.f : 2.f;
    float* part = ws + WS_PE;
    int bid = blockIdx.y * NTILE_ + blockIdx.x;
    part[bid]           = bs*wgt;
    part[NPART_ + bid]  = bss*wgt;
    part[2*NPART_ + bid]= bmn;
    part[3*NPART_ + bid]= bmx;
  }
}

// K3: reduce k2 partials + finalize scalar params
__global__ __launch_bounds__(256) void k3_fin(const float* __restrict__ alpha,
                                              const float* __restrict__ sigma_w, float* ws){
  __shared__ double ssm[256], sss[256];
  __shared__ float smn[256], smx[256];
  int tid = threadIdx.x;
  const float* part = ws + WS_PE;
  double s = 0.0, ss = 0.0;
  float mn = 3.4e38f, mx = -3.4e38f;
  for (int i2 = tid; i2 < NPART_; i2 += 256){
    s  += (double)part[i2];
    ss += (double)part[NPART_ + i2];
    mn = fminf(mn, part[2*NPART_ + i2]);
    mx = fmaxf(mx, part[3*NPART_ + i2]);
  }
  ssm[tid]=s; sss[tid]=ss; smn[tid]=mn; smx[tid]=mx;
  __syncthreads();
  for (int st = 128; st; st >>= 1){
    if (tid < st){
      ssm[tid] += ssm[tid+st];
      sss[tid] += sss[tid+st];
      smn[tid] = fminf(smn[tid], smn[tid+st]);
      smx[tid] = fmaxf(smx[tid], smx[tid+st]);
    }
    __syncthreads();
  }
  if (tid == 0){
    double N = (double)B_*S_*S_;
    double sum = ssm[0], sumsq = sss[0];
    double mean = sum/N;
    double var  = (sumsq - sum*sum/N) / (N - 1.0);
    float stdv = (float)sqrt(fmax(var, 0.0));
    float m = (float)mean;
    float lo = m - 2.f*stdv, hi = m + 2.f*stdv;
    float cmn = fminf(fmaxf(smn[0], lo), hi);
    float cmx = fminf(fmaxf(smx[0], lo), hi);
    float invr = 1.f/(cmx - cmn + 1e-6f);
    float a = 1.f/(1.f + expf(-alpha[0]));
    float swv = sigma_w[0];
    float sp = (swv > 20.f) ? swv : log1pf(expf(swv));
    float sg = sp + 0.001f;
    float efac = -0.5f/(sg*sg);
    float* p = ws + WS_STATS + 8;
    p[0]=lo; p[1]=hi; p[2]=cmn; p[3]=invr; p[4]=a; p[5]=1.f-a; p[6]=efac;
  }
}

// K4: MFMA flash pass. 8 waves: (ssub 0..3) x (t-half 0..1). s-tile 64, t-tile 64.
__global__ __launch_bounds__(512) void k4_flash(const u16* __restrict__ us, float* __restrict__ ws)
{
  __shared__ __align__(16) u16 SMEM[16384];  // Kls|Xls|XTls|el : 4x8KB
  __shared__ float sqt_l[64], invt_l[64];
  __shared__ float rmx_l[4][2][16];
  __shared__ float zb[4][2][16];
  u16* Kls  = SMEM;
  u16* Xls  = SMEM + 4096;
  u16* XTls = SMEM + 8192;
  u16* elp  = SMEM + 12288;
  int tid = threadIdx.x, lane = tid & 63, wv = tid >> 6;
  int lg = lane >> 4, lc = lane & 15;
  int ssub = wv >> 1, th = wv & 1;
  int b = blockIdx.y;
  size_t rb = (size_t)b * S_;
  int s0 = blockIdx.x * 64;
  const u16* xb = us + US_XB;
  const u16* qb = us + US_QB;
  const u16* kb = us + US_KB;
  const u16* xt = us + US_XT + (size_t)b*64*2048;
  int srow = s0 + ssub*16 + lc;
  short8 qf0 = *(const short8*)(qb + (rb+srow)*64 + lg*8);
  short8 qf1 = *(const short8*)(qb + (rb+srow)*64 + 32 + lg*8);
  short8 xf0 = *(const short8*)(xb + (rb+srow)*64 + lg*8);
  short8 xf1 = *(const short8*)(xb + (rb+srow)*64 + 32 + lg*8);
  float sq_s[4], inv_s[4];
  #pragma unroll
  for (int r=0;r<4;++r){
    float s = ws[WS_SQ + rb + s0 + ssub*16 + lg*4 + r];
    sq_s[r] = s; inv_s[r] = 1.f / fmaxf(sqrtf(s), 1e-12f);
  }
  const float* prm = ws + WS_STATS + 8;
  float lo=prm[0], hi=prm[1], cmn=prm[2], invr=prm[3], a=prm[4], oma=prm[5], efac=prm[6];
  f32x4 pe[4];
  #pragma unroll
  for (int t=0;t<4;++t){ pe[t][0]=0.f; pe[t][1]=0.f; pe[t][2]=0.f; pe[t][3]=0.f; }
  float mrun[4], zrun[4];
  #pragma unroll
  for (int r=0;r<4;++r){ mrun[r]=-3.4e38f; zrun[r]=0.f; }

  for (int t0 = 0; t0 < S_; t0 += 64){
    {
      int slot = tid;
      int row = slot>>3, pc = slot&7, lcn = pc ^ (row&7);
      ((short8*)Kls)[slot]  = *(const short8*)(kb + (rb + t0 + row)*64 + lcn*8);
      ((short8*)Xls)[slot]  = *(const short8*)(xb + (rb + t0 + row)*64 + lcn*8);
      ((short8*)XTls)[slot] = *(const short8*)(xt + (size_t)row*2048 + t0 + lcn*8);
    }
    if (tid < 64){
      float s = ws[WS_SQ + rb + t0 + tid];
      sqt_l[tid] = s;
      invt_l[tid] = 1.f / fmaxf(sqrtf(s), 1e-12f);
    }
    __syncthreads();
    f32x4 ga[2], sa[2];
    #pragma unroll
    for (int t=0;t<2;++t){ ga[t][0]=0.f; ga[t][1]=0.f; ga[t][2]=0.f; ga[t][3]=0.f;
                           sa[t][0]=0.f; sa[t][1]=0.f; sa[t][2]=0.f; sa[t][3]=0.f; }
    #pragma unroll
    for (int ts=0; ts<2; ++ts){
      int rowb = (2*th+ts)*16 + lc;
      int sw = rowb & 7;
      short8 bk0 = *(const short8*)(Kls + rowb*64 + ((lg ^ sw)<<3));
      short8 bx0 = *(const short8*)(Xls + rowb*64 + ((lg ^ sw)<<3));
      sa[ts] = MFMA16(qf0, bk0, sa[ts]);
      ga[ts] = MFMA16(xf0, bx0, ga[ts]);
      short8 bk1 = *(const short8*)(Kls + rowb*64 + (((4+lg) ^ sw)<<3));
      short8 bx1 = *(const short8*)(Xls + rowb*64 + (((4+lg) ^ sw)<<3));
      sa[ts] = MFMA16(qf1, bk1, sa[ts]);
      ga[ts] = MFMA16(xf1, bx1, ga[ts]);
    }
    float sc0[4], sc1[4];
    #pragma unroll
    for (int r=0;r<4;++r){
      sc0[r] = sa[0][r]*0.125f;
      sc1[r] = sa[1][r]*0.125f;
      float m = fmaxf(sc0[r], sc1[r]);
      m = fmaxf(m, __shfl_xor(m, 1, 64));
      m = fmaxf(m, __shfl_xor(m, 2, 64));
      m = fmaxf(m, __shfl_xor(m, 4, 64));
      m = fmaxf(m, __shfl_xor(m, 8, 64));
      if (lc == r) rmx_l[ssub][th][lg*4+r] = m;
    }
    __syncthreads();
    #pragma unroll
    for (int r=0;r<4;++r){
      float tmax = fmaxf(rmx_l[ssub][0][lg*4+r], rmx_l[ssub][1][lg*4+r]);
      float mnew = fmaxf(mrun[r], tmax);
      float scl = __expf(mrun[r] - mnew);
      mrun[r] = mnew;
      zrun[r] *= scl;
      pe[0][r]*=scl; pe[1][r]*=scl; pe[2][r]*=scl; pe[3][r]*=scl;
    }
    #pragma unroll
    for (int ts=0; ts<2; ++ts){
      int col = (2*th+ts)*16 + lc;
      float sqt = sqt_l[col], invt = invt_l[col];
      #pragma unroll
      for (int r=0;r<4;++r){
        float gg = (ts==0) ? ga[0][r] : ga[1][r];
        float cosv = (gg*inv_s[r]*invt + 1.f)*0.5f;
        float d2 = sq_s[r] + sqt - 2.f*gg;
        d2 = fmaxf(d2, 0.f);
        float eu = d2 > 0.f ? sqrtf(d2) : 0.f;
        eu = fminf(fmaxf(eu, lo), hi);
        float en = (eu - cmn)*invr;
        float hyb = a*cosv + oma*(1.f - en);
        float H = __expf(hyb*efac);
        float p = __expf(((ts==0)?sc0[r]:sc1[r]) - mrun[r]);
        zrun[r] += p;
        int rowl = lg*4 + r;
        int phys = rowl*64 + ((((col>>3) ^ (rowl&7)))<<3) + (col&7);
        elp[ssub*1024 + phys] = f2bf(p*H);
      }
    }
    // PV: pe[fs] += E(16x32 window) @ x(32 x 16f)
    {
      int swA = lc & 7;
      short8 Ae = *(const short8*)(elp + ssub*1024 + lc*64 + (((4*th + lg) ^ swA)<<3));
      #pragma unroll
      for (int fs=0; fs<4; ++fs){
        int rowf = fs*16 + lc;
        short8 Bx = *(const short8*)(XTls + rowf*64 + (((4*th + lg) ^ (rowf&7))<<3));
        pe[fs] = MFMA16(Ae, Bx, pe[fs]);
      }
    }
    __syncthreads();
  }
  // z reduce + cross-half combine
  #pragma unroll
  for (int r=0;r<4;++r){
    float z = zrun[r];
    z += __shfl_xor(z, 1, 64);
    z += __shfl_xor(z, 2, 64);
    z += __shfl_xor(z, 4, 64);
    z += __shfl_xor(z, 8, 64);
    if (lc == r) zb[ssub][th][lg*4+r] = z;
  }
  __syncthreads();
  float* tmp = (float*)SMEM;  // 4096 floats scratch (tiles dead now)
  if (th == 1){
    #pragma unroll
    for (int fs=0; fs<4; ++fs)
      #pragma unroll
      for (int r=0;r<4;++r)
        tmp[ssub*1024 + (lg*4+r)*64 + fs*16 + lc] = pe[fs][r];
  }
  __syncthreads();
  if (th == 0){
    float zi[4];
    #pragma unroll
    for (int r=0;r<4;++r) zi[r] = 1.f / (zb[ssub][0][lg*4+r] + zb[ssub][1][lg*4+r]);
    #pragma unroll
    for (int fs=0; fs<4; ++fs)
      #pragma unroll
      for (int r=0;r<4;++r){
        float v = pe[fs][r] + tmp[ssub*1024 + (lg*4+r)*64 + fs*16 + lc];
        ws[WS_PE + (rb + s0 + ssub*16 + lg*4 + r)*64 + fs*16 + lc] = v * zi[r];
      }
  }
}

// K5: pe_proj GEMM + both LayerNorms + add
__global__ __launch_bounds__(256) void k5_final(
    const float* __restrict__ w_rel, const float* __restrict__ b_rel,
    const float* __restrict__ w_proj, const float* __restrict__ b_proj,
    const float* __restrict__ g1, const float* __restrict__ bt1,
    const float* __restrict__ g2, const float* __restrict__ bt2,
    const float* __restrict__ ws, float* __restrict__ out)
{
  __shared__ __align__(16) float pel[16*68];
  __shared__ __align__(16) float wpl[4096];
  __shared__ __align__(16) float res[16*512];
  __shared__ float rsl[48];
  __shared__ float g1l[512], b1l[512], g2l[512], b2l[512], brl[512], wrl[1536];
  int tid = threadIdx.x, lane = tid & 63, wv = tid >> 6;
  int row0 = blockIdx.x * 16;
  {
    int r = tid >> 4, c = tid & 15;
    *(float4*)(pel + r*68 + c*4) = *(const float4*)(ws + WS_PE + (size_t)(row0+r)*F_ + c*4);
  }
  if (tid < 48) rsl[tid] = ws[WS_REL + row0*3 + tid];
  for (int i = tid; i < 512; i += 256){
    g1l[i]=g1[i]; b1l[i]=bt1[i]; g2l[i]=g2[i]; b2l[i]=bt2[i]; brl[i]=b_rel[i];
  }
  for (int i = tid; i < 1536; i += 256) wrl[i] = w_rel[i];
  for (int ch = 0; ch < 8; ++ch){
    __syncthreads();
    for (int i=0;i<4;++i){
      int idx = tid + i*256; int d = idx>>4, c = idx&15;
      float4 v = *(const float4*)(w_proj + (size_t)(ch*64+d)*F_ + c*4);
      int pb = swz_phys(d, c);
      wpl[pb]=v.x; wpl[pb+1]=v.y; wpl[pb+2]=v.z; wpl[pb+3]=v.w;
    }
    __syncthreads();
    int d = ch*64 + lane;
    float bp = b_proj[d];
    float ac[4];
    #pragma unroll
    for (int j=0;j<4;++j) ac[j] = bp;
    int swl = lane & 15;
    #pragma unroll
    for (int c=0;c<16;++c){
      float4 wv4 = *(const float4*)(wpl + lane*64 + ((c ^ swl)<<2));
      #pragma unroll
      for (int j=0;j<4;++j){
        float4 pv = *(const float4*)(pel + (wv*4+j)*68 + c*4);
        ac[j] += pv.x*wv4.x + pv.y*wv4.y + pv.z*wv4.z + pv.w*wv4.w;
      }
    }
    #pragma unroll
    for (int j=0;j<4;++j) res[(wv*4+j)*512 + d] = ac[j];
  }
  __syncthreads();
  #pragma unroll
  for (int j=0;j<4;++j){
    int r = wv*4 + j;
    int rg = row0 + r;
    float s1=0.f, q1=0.f;
    float vals[8];
    #pragma unroll
    for (int i=0;i<8;++i){ float v = res[r*512 + i*64 + lane]; vals[i]=v; s1+=v; q1+=v*v; }
    for (int o=32;o;o>>=1){ s1 += __shfl_xor(s1,o,64); q1 += __shfl_xor(q1,o,64); }
    float mu1 = s1*(1.f/512.f);
    float var1 = q1*(1.f/512.f) - mu1*mu1;
    float rsg1 = rsqrtf(fmaxf(var1, 0.f) + 1e-5f);
    float c0 = rsl[r*3+0], c1 = rsl[r*3+1], c2 = rsl[r*3+2];
    float rv[8]; float s2=0.f, q2=0.f;
    #pragma unroll
    for (int i=0;i<8;++i){
      int d = i*64 + lane;
      float v = c0*wrl[d*3+0] + c1*wrl[d*3+1] + c2*wrl[d*3+2] + 5.f*brl[d];
      rv[i]=v; s2+=v; q2+=v*v;
    }
    for (int o=32;o;o>>=1){ s2 += __shfl_xor(s2,o,64); q2 += __shfl_xor(q2,o,64); }
    float mu2 = s2*(1.f/512.f);
    float var2 = q2*(1.f/512.f) - mu2*mu2;
    float rsg2 = rsqrtf(fmaxf(var2, 0.f) + 1e-5f);
    #pragma unroll
    for (int i=0;i<8;++i){
      int d = i*64 + lane;
      float o1 = (vals[i]-mu1)*rsg1*g2l[d] + b2l[d];
      float o2 = (rv[i]-mu2)*rsg2*g1l[d] + b1l[d];
      out[(size_t)rg*512 + d] = o1 + o2;
    }
  }
}

extern "C" void kernel_launch(void* const* d_in, const int* in_sizes, int n_in,
                              void* d_out, int out_size, void* d_ws, size_t ws_size,
                              hipStream_t stream)
{
  const float* x      = (const float*)d_in[0];
  const float* w_rel  = (const float*)d_in[1];
  const float* b_rel  = (const float*)d_in[2];
  const float* w_proj = (const float*)d_in[3];
  const float* b_proj = (const float*)d_in[4];
  const float* g1     = (const float*)d_in[5];
  const float* bt1    = (const float*)d_in[6];
  const float* g2     = (const float*)d_in[7];
  const float* bt2    = (const float*)d_in[8];
  const float* alpha  = (const float*)d_in[9];
  const float* sigma_w= (const float*)d_in[10];
  const float* wq     = (const float*)d_in[11];
  const float* bq     = (const float*)d_in[12];
  const float* wk     = (const float*)d_in[13];
  const float* bk     = (const float*)d_in[14];
  const float* scale_w= (const float*)d_in[15];
  float* wsf = (float*)d_ws;
  u16*  usb = (u16*)(wsf + US_BASE_FLOATS);
  float* out = (float*)d_out;

  hipLaunchKernelGGL(k1_prep, dim3(BS_/16), dim3(256), 0, stream, x, wq, bq, wk, bk, scale_w, wsf, usb);
  hipLaunchKernelGGL(k2_stats, dim3(NTILE_, B_), dim3(256), 0, stream, usb, wsf);
  hipLaunchKernelGGL(k3_fin, dim3(1), dim3(256), 0, stream, alpha, sigma_w, wsf);
  hipLaunchKernelGGL(k4_flash, dim3(S_/64, B_), dim3(512), 0, stream, usb, wsf);
  hipLaunchKernelGGL(k5_final, dim3(BS_/16), dim3(256), 0, stream,
                     w_rel, b_rel, w_proj, b_proj, g1, bt1, g2, bt2, wsf, out);
}

// Round 5
// 252.476 us; speedup vs baseline: 4.7407x; 1.1679x over previous
//
#include <hip/hip_runtime.h>
#include <math.h>

#define B_ 8
#define S_ 2048
#define F_ 64
#define D_ 512
#define NS_ 5
#define BS_ (B_*S_)
#define NTILE_ 528
#define NPART_ (NTILE_*B_)

typedef unsigned short u16;
typedef __attribute__((ext_vector_type(8))) short short8;
typedef __attribute__((ext_vector_type(4))) float f32x4;

// float-region offsets (in floats)
#define WS_SQ    0
#define WS_REL   (BS_)
#define WS_PE    (4*BS_)     // k2 partials (pre-k3), then f32 pe_event (k4)
#define WS_STATS (68*BS_)
#define US_BASE_FLOATS (68*BS_ + 16)
// ushort-region offsets (in ushorts, from usb)
#define US_XB 0
#define US_QB (BS_*64)     // q for k4; reused as bf16 pe_event for k5
#define US_KB (2*BS_*64)   // k for k4; reused as bf16 w_proj for k5
#define US_XT (3*BS_*64)

#define MFMA16(a,b,c) __builtin_amdgcn_mfma_f32_16x16x32_bf16(a,b,c,0,0,0)

__device__ __forceinline__ u16 f2bf(float f){
  unsigned u = __float_as_uint(f);
  return (u16)((u + 0x7FFFu + ((u>>16)&1u)) >> 16);
}
// f32-tile swizzle used by k1
__device__ __forceinline__ int swz_phys(int row, int c){ return row*64 + (((c ^ (row & 15))) << 2); }

// K1: q/k (fp32 compute -> bf16 store), sq, rel sums, xb16, xT16
__global__ __launch_bounds__(256) void k1_prep(
    const float* __restrict__ x, const float* __restrict__ wq, const float* __restrict__ bq,
    const float* __restrict__ wk, const float* __restrict__ bk,
    const float* __restrict__ scale_w, float* __restrict__ ws, u16* __restrict__ usb)
{
  __shared__ __align__(16) float xl[16*68];
  __shared__ __align__(16) float wql[4096];
  __shared__ __align__(16) float wkl[4096];
  int tid = threadIdx.x, lane = tid & 63, wv = tid >> 6;
  int row0 = blockIdx.x * 16;
  {
    int r = tid >> 4, c = tid & 15;
    *(float4*)(xl + r*68 + c*4) = *(const float4*)(x + (size_t)(row0 + r)*F_ + c*4);
  }
  for (int i = 0; i < 4; ++i){
    int idx = tid + i*256;
    int g = idx >> 4, c = idx & 15;
    float4 v = *(const float4*)(wq + g*F_ + c*4);
    int pb = swz_phys(g, c);
    wql[pb]=v.x; wql[pb+1]=v.y; wql[pb+2]=v.z; wql[pb+3]=v.w;
    float4 u = *(const float4*)(wk + g*F_ + c*4);
    wkl[pb]=u.x; wkl[pb+1]=u.y; wkl[pb+2]=u.z; wkl[pb+3]=u.w;
  }
  __syncthreads();
  int g = lane;
  int swl = g & 15;
  float qa[4], ka[4];
  #pragma unroll
  for (int j=0;j<4;++j){ qa[j]=bq[g]; ka[j]=bk[g]; }
  #pragma unroll
  for (int c=0;c<16;++c){
    float4 wqv = *(const float4*)(wql + g*64 + ((c ^ swl)<<2));
    float4 wkv = *(const float4*)(wkl + g*64 + ((c ^ swl)<<2));
    #pragma unroll
    for (int j=0;j<4;++j){
      float4 xv = *(const float4*)(xl + (wv*4+j)*68 + c*4);
      qa[j] += xv.x*wqv.x + xv.y*wqv.y + xv.z*wqv.z + xv.w*wqv.w;
      ka[j] += xv.x*wkv.x + xv.y*wkv.y + xv.z*wkv.z + xv.w*wkv.w;
    }
  }
  #pragma unroll
  for (int j=0;j<4;++j){
    int rg = row0 + wv*4 + j;
    usb[US_QB + (size_t)rg*64 + g] = f2bf(qa[j]);
    usb[US_KB + (size_t)rg*64 + g] = f2bf(ka[j]);
  }
  #pragma unroll
  for (int j=0;j<4;++j){
    int r = wv*4 + j;
    float v = xl[r*68 + lane];
    float s = v*v;
    for (int o=32;o;o>>=1) s += __shfl_xor(s, o, 64);
    if (lane == 0) ws[WS_SQ + row0 + r] = s;
  }
  #pragma unroll
  for (int j=0;j<4;++j){
    int r = wv*4 + j;
    int rg = row0 + r;
    int b = rg >> 11, s_loc = rg & (S_-1);
    float d0 = xl[r*68 + 0], e0 = xl[r*68 + 1];
    float dd = 0.f, de = 0.f, wd = 0.f;
    int n = lane + 1;
    if (lane < NS_ && s_loc >= n){
      const float* xp = x + ((size_t)(b*S_ + s_loc - n))*F_;
      float dp_ = xp[0], ep = xp[1];
      dd = dp_ - d0;
      de = ep - e0;
      wd = scale_w[lane] * __expf(-fabsf(dd) * (1.0f/(float)(1<<n)));
    }
    for (int o=4;o;o>>=1){
      dd += __shfl_down(dd, o, 64);
      de += __shfl_down(de, o, 64);
      wd += __shfl_down(wd, o, 64);
    }
    if (lane == 0){
      ws[WS_REL + rg*3+0] = dd;
      ws[WS_REL + rg*3+1] = de;
      ws[WS_REL + rg*3+2] = wd;
    }
  }
  // bf16 x (row-major)
  {
    int r = tid >> 4, cb = (tid & 15)*4;
    unsigned w0 = (unsigned)f2bf(xl[r*68+cb])   | ((unsigned)f2bf(xl[r*68+cb+1])<<16);
    unsigned w1 = (unsigned)f2bf(xl[r*68+cb+2]) | ((unsigned)f2bf(xl[r*68+cb+3])<<16);
    uint2 pk; pk.x = w0; pk.y = w1;
    *(uint2*)(usb + US_XB + (size_t)(row0+r)*64 + cb) = pk;
  }
  // bf16 x transposed per batch: xT[b][f][t]
  {
    int f = tid & 63, rg4 = (tid >> 6)*4;
    unsigned wa = (unsigned)f2bf(xl[(rg4+0)*68+f]) | ((unsigned)f2bf(xl[(rg4+1)*68+f])<<16);
    unsigned wb = (unsigned)f2bf(xl[(rg4+2)*68+f]) | ((unsigned)f2bf(xl[(rg4+3)*68+f])<<16);
    uint2 pk; pk.x = wa; pk.y = wb;
    int bb = row0 >> 11;
    int tloc = (row0 & (S_-1)) + rg4;
    *(uint2*)(usb + US_XT + (size_t)bb*64*2048 + (size_t)f*2048 + tloc) = pk;
  }
}

// K2: euclid stats via MFMA Gram, upper-triangle tiles only (off-diag weight 2).
// Per-block partials -> WS_PE region (consumed by k3 before k4 overwrites).
__global__ __launch_bounds__(256) void k2_stats(const u16* __restrict__ us, float* __restrict__ ws)
{
  __shared__ __align__(16) u16 Xls[4096];
  __shared__ float sqs_l[64], sqt_l[64];
  __shared__ float rsum[4], rss[4], rmn[4], rmx[4];
  int tid = threadIdx.x, lane = tid & 63, wv = tid >> 6;
  int lg = lane >> 4, lc = lane & 15;
  int b = blockIdx.y;
  int rem = blockIdx.x, i = 0;
  while (rem >= 32 - i){ rem -= 32 - i; ++i; }
  int j = i + rem;
  int s0 = i*64, t0 = j*64;
  size_t rb = (size_t)b * S_;
  const u16* xb = us + US_XB;
  #pragma unroll
  for (int p2=0;p2<2;++p2){
    int slot = tid + p2*256;
    int row = slot>>3, pc = slot&7, lcn = pc ^ (row&7);
    ((short8*)Xls)[slot] = *(const short8*)(xb + (rb + t0 + row)*64 + lcn*8);
  }
  if (tid < 64) sqs_l[tid] = ws[WS_SQ + rb + s0 + tid];
  else if (tid < 128) sqt_l[tid-64] = ws[WS_SQ + rb + t0 + (tid-64)];
  short8 a0 = *(const short8*)(xb + (rb + s0 + wv*16 + lc)*64 + lg*8);
  short8 a1 = *(const short8*)(xb + (rb + s0 + wv*16 + lc)*64 + 32 + lg*8);
  __syncthreads();
  f32x4 acc[4];
  #pragma unroll
  for (int t=0;t<4;++t){ acc[t][0]=0.f; acc[t][1]=0.f; acc[t][2]=0.f; acc[t][3]=0.f; }
  #pragma unroll
  for (int ts=0; ts<4; ++ts){
    int rowb = ts*16 + lc;
    int sw = rowb & 7;
    short8 b0 = *(const short8*)(Xls + rowb*64 + ((lg ^ sw)<<3));
    short8 b1 = *(const short8*)(Xls + rowb*64 + (((4+lg) ^ sw)<<3));
    acc[ts] = MFMA16(a0, b0, acc[ts]);
    acc[ts] = MFMA16(a1, b1, acc[ts]);
  }
  float sq_s[4];
  #pragma unroll
  for (int r=0;r<4;++r) sq_s[r] = sqs_l[wv*16 + lg*4 + r];
  float lsum=0.f, lss=0.f, lmn=3.4e38f, lmx=-3.4e38f;
  #pragma unroll
  for (int ts=0; ts<4; ++ts){
    float sqt = sqt_l[ts*16 + lc];
    #pragma unroll
    for (int r=0;r<4;++r){
      float gg = acc[ts][r];
      float d2 = sq_s[r] + sqt - 2.f*gg;
      d2 = fmaxf(d2, 0.f);
      float eu = d2 > 0.f ? sqrtf(d2) : 0.f;
      lsum += eu; lss += eu*eu;
      lmn = fminf(lmn, eu); lmx = fmaxf(lmx, eu);
    }
  }
  for (int o=32;o;o>>=1){
    lsum += __shfl_xor(lsum, o, 64);
    lss  += __shfl_xor(lss, o, 64);
    lmn = fminf(lmn, __shfl_xor(lmn, o, 64));
    lmx = fmaxf(lmx, __shfl_xor(lmx, o, 64));
  }
  if (lane == 0){ rsum[wv]=lsum; rss[wv]=lss; rmn[wv]=lmn; rmx[wv]=lmx; }
  __syncthreads();
  if (tid == 0){
    float bs=0.f, bss=0.f, bmn=3.4e38f, bmx=-3.4e38f;
    for (int w2=0;w2<4;++w2){ bs+=rsum[w2]; bss+=rss[w2]; bmn=fminf(bmn,rmn[w2]); bmx=fmaxf(bmx,rmx[w2]); }
    float wgt = (i==j) ? 1.f : 2.f;
    float* part = ws + WS_PE;
    int bid = blockIdx.y * NTILE_ + blockIdx.x;
    part[bid]           = bs*wgt;
    part[NPART_ + bid]  = bss*wgt;
    part[2*NPART_ + bid]= bmn;
    part[3*NPART_ + bid]= bmx;
  }
}

// K3: reduce k2 partials + finalize scalar params
__global__ __launch_bounds__(256) void k3_fin(const float* __restrict__ alpha,
                                              const float* __restrict__ sigma_w, float* ws){
  __shared__ double ssm[256], sss[256];
  __shared__ float smn[256], smx[256];
  int tid = threadIdx.x;
  const float* part = ws + WS_PE;
  double s = 0.0, ss = 0.0;
  float mn = 3.4e38f, mx = -3.4e38f;
  for (int i2 = tid; i2 < NPART_; i2 += 256){
    s  += (double)part[i2];
    ss += (double)part[NPART_ + i2];
    mn = fminf(mn, part[2*NPART_ + i2]);
    mx = fmaxf(mx, part[3*NPART_ + i2]);
  }
  ssm[tid]=s; sss[tid]=ss; smn[tid]=mn; smx[tid]=mx;
  __syncthreads();
  for (int st = 128; st; st >>= 1){
    if (tid < st){
      ssm[tid] += ssm[tid+st];
      sss[tid] += sss[tid+st];
      smn[tid] = fminf(smn[tid], smn[tid+st]);
      smx[tid] = fmaxf(smx[tid], smx[tid+st]);
    }
    __syncthreads();
  }
  if (tid == 0){
    double N = (double)B_*S_*S_;
    double sum = ssm[0], sumsq = sss[0];
    double mean = sum/N;
    double var  = (sumsq - sum*sum/N) / (N - 1.0);
    float stdv = (float)sqrt(fmax(var, 0.0));
    float m = (float)mean;
    float lo = m - 2.f*stdv, hi = m + 2.f*stdv;
    float cmn = fminf(fmaxf(smn[0], lo), hi);
    float cmx = fminf(fmaxf(smx[0], lo), hi);
    float invr = 1.f/(cmx - cmn + 1e-6f);
    float a = 1.f/(1.f + expf(-alpha[0]));
    float swv = sigma_w[0];
    float sp = (swv > 20.f) ? swv : log1pf(expf(swv));
    float sg = sp + 0.001f;
    float efac = -0.5f/(sg*sg);
    float* p = ws + WS_STATS + 8;
    p[0]=lo; p[1]=hi; p[2]=cmn; p[3]=invr; p[4]=a; p[5]=1.f-a; p[6]=efac;
  }
}

// K4: MFMA flash pass — EXACT round-3 validated version.
// 8 waves: (ssub 0..3) x (t-half 0..1). s-tile 64, t-tile 64. Writes f32 pe.
__global__ __launch_bounds__(512) void k4_flash(const u16* __restrict__ us, float* __restrict__ ws)
{
  __shared__ __align__(16) u16 SMEM[16384];  // Kls|Xls|XTls|el : 4x8KB
  __shared__ float sqt_l[64], invt_l[64];
  __shared__ float rmx_l[4][2][16];
  __shared__ float zb[4][2][16];
  u16* Kls  = SMEM;
  u16* Xls  = SMEM + 4096;
  u16* XTls = SMEM + 8192;
  u16* elp  = SMEM + 12288;
  int tid = threadIdx.x, lane = tid & 63, wv = tid >> 6;
  int lg = lane >> 4, lc = lane & 15;
  int ssub = wv >> 1, th = wv & 1;
  int b = blockIdx.y;
  size_t rb = (size_t)b * S_;
  int s0 = blockIdx.x * 64;
  const u16* xb = us + US_XB;
  const u16* qb = us + US_QB;
  const u16* kb = us + US_KB;
  const u16* xt = us + US_XT + (size_t)b*64*2048;
  int srow = s0 + ssub*16 + lc;
  short8 qf0 = *(const short8*)(qb + (rb+srow)*64 + lg*8);
  short8 qf1 = *(const short8*)(qb + (rb+srow)*64 + 32 + lg*8);
  short8 xf0 = *(const short8*)(xb + (rb+srow)*64 + lg*8);
  short8 xf1 = *(const short8*)(xb + (rb+srow)*64 + 32 + lg*8);
  float sq_s[4], inv_s[4];
  #pragma unroll
  for (int r=0;r<4;++r){
    float s = ws[WS_SQ + rb + s0 + ssub*16 + lg*4 + r];
    sq_s[r] = s; inv_s[r] = 1.f / fmaxf(sqrtf(s), 1e-12f);
  }
  const float* prm = ws + WS_STATS + 8;
  float lo=prm[0], hi=prm[1], cmn=prm[2], invr=prm[3], a=prm[4], oma=prm[5], efac=prm[6];
  f32x4 pe[4];
  #pragma unroll
  for (int t=0;t<4;++t){ pe[t][0]=0.f; pe[t][1]=0.f; pe[t][2]=0.f; pe[t][3]=0.f; }
  float mrun[4], zrun[4];
  #pragma unroll
  for (int r=0;r<4;++r){ mrun[r]=-3.4e38f; zrun[r]=0.f; }

  for (int t0 = 0; t0 < S_; t0 += 64){
    {
      int slot = tid;
      int row = slot>>3, pc = slot&7, lcn = pc ^ (row&7);
      ((short8*)Kls)[slot]  = *(const short8*)(kb + (rb + t0 + row)*64 + lcn*8);
      ((short8*)Xls)[slot]  = *(const short8*)(xb + (rb + t0 + row)*64 + lcn*8);
      ((short8*)XTls)[slot] = *(const short8*)(xt + (size_t)row*2048 + t0 + lcn*8);
    }
    if (tid < 64){
      float s = ws[WS_SQ + rb + t0 + tid];
      sqt_l[tid] = s;
      invt_l[tid] = 1.f / fmaxf(sqrtf(s), 1e-12f);
    }
    __syncthreads();
    f32x4 ga[2], sa[2];
    #pragma unroll
    for (int t=0;t<2;++t){ ga[t][0]=0.f; ga[t][1]=0.f; ga[t][2]=0.f; ga[t][3]=0.f;
                           sa[t][0]=0.f; sa[t][1]=0.f; sa[t][2]=0.f; sa[t][3]=0.f; }
    #pragma unroll
    for (int ts=0; ts<2; ++ts){
      int rowb = (2*th+ts)*16 + lc;
      int sw = rowb & 7;
      short8 bk0 = *(const short8*)(Kls + rowb*64 + ((lg ^ sw)<<3));
      short8 bx0 = *(const short8*)(Xls + rowb*64 + ((lg ^ sw)<<3));
      sa[ts] = MFMA16(qf0, bk0, sa[ts]);
      ga[ts] = MFMA16(xf0, bx0, ga[ts]);
      short8 bk1 = *(const short8*)(Kls + rowb*64 + (((4+lg) ^ sw)<<3));
      short8 bx1 = *(const short8*)(Xls + rowb*64 + (((4+lg) ^ sw)<<3));
      sa[ts] = MFMA16(qf1, bk1, sa[ts]);
      ga[ts] = MFMA16(xf1, bx1, ga[ts]);
    }
    float sc0[4], sc1[4];
    #pragma unroll
    for (int r=0;r<4;++r){
      sc0[r] = sa[0][r]*0.125f;
      sc1[r] = sa[1][r]*0.125f;
      float m = fmaxf(sc0[r], sc1[r]);
      m = fmaxf(m, __shfl_xor(m, 1, 64));
      m = fmaxf(m, __shfl_xor(m, 2, 64));
      m = fmaxf(m, __shfl_xor(m, 4, 64));
      m = fmaxf(m, __shfl_xor(m, 8, 64));
      if (lc == r) rmx_l[ssub][th][lg*4+r] = m;
    }
    __syncthreads();
    #pragma unroll
    for (int r=0;r<4;++r){
      float tmax = fmaxf(rmx_l[ssub][0][lg*4+r], rmx_l[ssub][1][lg*4+r]);
      float mnew = fmaxf(mrun[r], tmax);
      float scl = __expf(mrun[r] - mnew);
      mrun[r] = mnew;
      zrun[r] *= scl;
      pe[0][r]*=scl; pe[1][r]*=scl; pe[2][r]*=scl; pe[3][r]*=scl;
    }
    #pragma unroll
    for (int ts=0; ts<2; ++ts){
      int col = (2*th+ts)*16 + lc;
      float sqt = sqt_l[col], invt = invt_l[col];
      #pragma unroll
      for (int r=0;r<4;++r){
        float gg = (ts==0) ? ga[0][r] : ga[1][r];
        float cosv = (gg*inv_s[r]*invt + 1.f)*0.5f;
        float d2 = sq_s[r] + sqt - 2.f*gg;
        d2 = fmaxf(d2, 0.f);
        float eu = d2 > 0.f ? sqrtf(d2) : 0.f;
        eu = fminf(fmaxf(eu, lo), hi);
        float en = (eu - cmn)*invr;
        float hyb = a*cosv + oma*(1.f - en);
        float H = __expf(hyb*efac);
        float p = __expf(((ts==0)?sc0[r]:sc1[r]) - mrun[r]);
        zrun[r] += p;
        int rowl = lg*4 + r;
        int phys = rowl*64 + ((((col>>3) ^ (rowl&7)))<<3) + (col&7);
        elp[ssub*1024 + phys] = f2bf(p*H);
      }
    }
    // PV: pe[fs] += E(16x32 window) @ x(32 x 16f)
    {
      int swA = lc & 7;
      short8 Ae = *(const short8*)(elp + ssub*1024 + lc*64 + (((4*th + lg) ^ swA)<<3));
      #pragma unroll
      for (int fs=0; fs<4; ++fs){
        int rowf = fs*16 + lc;
        short8 Bx = *(const short8*)(XTls + rowf*64 + (((4*th + lg) ^ (rowf&7))<<3));
        pe[fs] = MFMA16(Ae, Bx, pe[fs]);
      }
    }
    __syncthreads();
  }
  // z reduce + cross-half combine
  #pragma unroll
  for (int r=0;r<4;++r){
    float z = zrun[r];
    z += __shfl_xor(z, 1, 64);
    z += __shfl_xor(z, 2, 64);
    z += __shfl_xor(z, 4, 64);
    z += __shfl_xor(z, 8, 64);
    if (lc == r) zb[ssub][th][lg*4+r] = z;
  }
  __syncthreads();
  float* tmp = (float*)SMEM;  // 4096 floats scratch (tiles dead now)
  if (th == 1){
    #pragma unroll
    for (int fs=0; fs<4; ++fs)
      #pragma unroll
      for (int r=0;r<4;++r)
        tmp[ssub*1024 + (lg*4+r)*64 + fs*16 + lc] = pe[fs][r];
  }
  __syncthreads();
  if (th == 0){
    float zi[4];
    #pragma unroll
    for (int r=0;r<4;++r) zi[r] = 1.f / (zb[ssub][0][lg*4+r] + zb[ssub][1][lg*4+r]);
    #pragma unroll
    for (int fs=0; fs<4; ++fs)
      #pragma unroll
      for (int r=0;r<4;++r){
        float v = pe[fs][r] + tmp[ssub*1024 + (lg*4+r)*64 + fs*16 + lc];
        ws[WS_PE + (rb + s0 + ssub*16 + lg*4 + r)*64 + fs*16 + lc] = v * zi[r];
      }
  }
}

// KPE: convert f32 pe_event (WS_PE) -> bf16 into US_QB (q dead after k4)
__global__ __launch_bounds__(256) void kpe_conv(const float* __restrict__ pef, u16* __restrict__ usb){
  size_t i = ((size_t)blockIdx.x*256 + threadIdx.x)*4;
  float4 v = *(const float4*)(pef + i);
  uint2 pk;
  pk.x = (unsigned)f2bf(v.x) | ((unsigned)f2bf(v.y)<<16);
  pk.y = (unsigned)f2bf(v.z) | ((unsigned)f2bf(v.w)<<16);
  *(uint2*)(usb + US_QB + i) = pk;
}

// KW: convert w_proj (512x64 f32) -> bf16 into US_KB (k dead after k4)
__global__ __launch_bounds__(256) void kw_conv(const float* __restrict__ wp, u16* __restrict__ usb){
  int i = (blockIdx.x*256 + threadIdx.x)*4;
  float4 v = *(const float4*)(wp + i);
  uint2 pk;
  pk.x = (unsigned)f2bf(v.x) | ((unsigned)f2bf(v.y)<<16);
  pk.y = (unsigned)f2bf(v.z) | ((unsigned)f2bf(v.w)<<16);
  *(uint2*)(usb + US_KB + i) = pk;
}

// K5: pe_proj via MFMA (bf16 pe @ bf16 w_proj, both from L2 via clean u16* param)
//     + both LayerNorms + add
__global__ __launch_bounds__(256) void k5_final(
    const float* __restrict__ w_rel, const float* __restrict__ b_rel,
    const float* __restrict__ b_proj,
    const float* __restrict__ g1, const float* __restrict__ bt1,
    const float* __restrict__ g2, const float* __restrict__ bt2,
    const float* __restrict__ ws, const u16* __restrict__ usb, float* __restrict__ out)
{
  __shared__ __align__(16) float res[16*512];
  __shared__ float rsl[48];
  __shared__ float g1l[512], b1l[512], g2l[512], b2l[512], brl[512], wrl[1536];
  int tid = threadIdx.x, lane = tid & 63, wv = tid >> 6;
  int lg = lane >> 4, lc = lane & 15;
  int row0 = blockIdx.x * 16;
  const u16* peb = usb + US_QB;
  const u16* wb  = usb + US_KB;
  short8 a0 = *(const short8*)(peb + (size_t)(row0+lc)*64 + lg*8);
  short8 a1 = *(const short8*)(peb + (size_t)(row0+lc)*64 + 32 + lg*8);
  if (tid < 48) rsl[tid] = ws[WS_REL + row0*3 + tid];
  for (int i = tid; i < 512; i += 256){
    g1l[i]=g1[i]; b1l[i]=bt1[i]; g2l[i]=g2[i]; b2l[i]=bt2[i]; brl[i]=b_rel[i];
  }
  for (int i = tid; i < 1536; i += 256) wrl[i] = w_rel[i];
  int wc0 = wv*128;
  #pragma unroll
  for (int cg=0; cg<8; ++cg){
    int d = wc0 + cg*16 + lc;
    short8 b0 = *(const short8*)(wb + (size_t)d*64 + lg*8);
    short8 b1 = *(const short8*)(wb + (size_t)d*64 + 32 + lg*8);
    f32x4 acc = {0.f,0.f,0.f,0.f};
    acc = MFMA16(a0, b0, acc);
    acc = MFMA16(a1, b1, acc);
    float bp = b_proj[d];
    #pragma unroll
    for (int r=0;r<4;++r) res[(lg*4+r)*512 + d] = acc[r] + bp;
  }
  __syncthreads();
  #pragma unroll
  for (int j=0;j<4;++j){
    int r = wv*4 + j;
    int rg = row0 + r;
    float s1=0.f, q1=0.f;
    float vals[8];
    #pragma unroll
    for (int i=0;i<8;++i){ float v = res[r*512 + i*64 + lane]; vals[i]=v; s1+=v; q1+=v*v; }
    for (int o=32;o;o>>=1){ s1 += __shfl_xor(s1,o,64); q1 += __shfl_xor(q1,o,64); }
    float mu1 = s1*(1.f/512.f);
    float var1 = q1*(1.f/512.f) - mu1*mu1;
    float rsg1 = rsqrtf(fmaxf(var1, 0.f) + 1e-5f);
    float c0 = rsl[r*3+0], c1 = rsl[r*3+1], c2 = rsl[r*3+2];
    float rv[8]; float s2=0.f, q2=0.f;
    #pragma unroll
    for (int i=0;i<8;++i){
      int d = i*64 + lane;
      float v = c0*wrl[d*3+0] + c1*wrl[d*3+1] + c2*wrl[d*3+2] + 5.f*brl[d];
      rv[i]=v; s2+=v; q2+=v*v;
    }
    for (int o=32;o;o>>=1){ s2 += __shfl_xor(s2,o,64); q2 += __shfl_xor(q2,o,64); }
    float mu2 = s2*(1.f/512.f);
    float var2 = q2*(1.f/512.f) - mu2*mu2;
    float rsg2 = rsqrtf(fmaxf(var2, 0.f) + 1e-5f);
    #pragma unroll
    for (int i=0;i<8;++i){
      int d = i*64 + lane;
      float o1 = (vals[i]-mu1)*rsg1*g2l[d] + b2l[d];
      float o2 = (rv[i]-mu2)*rsg2*g1l[d] + b1l[d];
      out[(size_t)rg*512 + d] = o1 + o2;
    }
  }
}

extern "C" void kernel_launch(void* const* d_in, const int* in_sizes, int n_in,
                              void* d_out, int out_size, void* d_ws, size_t ws_size,
                              hipStream_t stream)
{
  const float* x      = (const float*)d_in[0];
  const float* w_rel  = (const float*)d_in[1];
  const float* b_rel  = (const float*)d_in[2];
  const float* w_proj = (const float*)d_in[3];
  const float* b_proj = (const float*)d_in[4];
  const float* g1     = (const float*)d_in[5];
  const float* bt1    = (const float*)d_in[6];
  const float* g2     = (const float*)d_in[7];
  const float* bt2    = (const float*)d_in[8];
  const float* alpha  = (const float*)d_in[9];
  const float* sigma_w= (const float*)d_in[10];
  const float* wq     = (const float*)d_in[11];
  const float* bq     = (const float*)d_in[12];
  const float* wk     = (const float*)d_in[13];
  const float* bk     = (const float*)d_in[14];
  const float* scale_w= (const float*)d_in[15];
  float* wsf = (float*)d_ws;
  u16*  usb = (u16*)(wsf + US_BASE_FLOATS);
  float* out = (float*)d_out;

  hipLaunchKernelGGL(k1_prep, dim3(BS_/16), dim3(256), 0, stream, x, wq, bq, wk, bk, scale_w, wsf, usb);
  hipLaunchKernelGGL(k2_stats, dim3(NTILE_, B_), dim3(256), 0, stream, usb, wsf);
  hipLaunchKernelGGL(k3_fin, dim3(1), dim3(256), 0, stream, alpha, sigma_w, wsf);
  hipLaunchKernelGGL(k4_flash, dim3(S_/64, B_), dim3(512), 0, stream, usb, wsf);
  hipLaunchKernelGGL(kpe_conv, dim3(BS_*64/1024), dim3(256), 0, stream, wsf + WS_PE, usb);
  hipLaunchKernelGGL(kw_conv, dim3(32), dim3(256), 0, stream, w_proj, usb);
  hipLaunchKernelGGL(k5_final, dim3(BS_/16), dim3(256), 0, stream,
                     w_rel, b_rel, b_proj, g1, bt1, g2, bt2, wsf, usb, out);
}

// Round 6
// 226.351 us; speedup vs baseline: 5.2879x; 1.1154x over previous
//
#include <hip/hip_runtime.h>
#include <math.h>

#define B_ 8
#define S_ 2048
#define F_ 64
#define D_ 512
#define NS_ 5
#define BS_ (B_*S_)
#define NTILE_ 528
#define NPART_ (NTILE_*B_)

typedef unsigned short u16;
typedef __attribute__((ext_vector_type(8))) short short8;
typedef __attribute__((ext_vector_type(4))) float f32x4;

// float-region offsets (in floats)
#define WS_SQ    0
#define WS_REL   (BS_)
#define WS_PE    (4*BS_)     // k2 partials (pre-k3), then f32 pe_event (k4)
#define WS_STATS (68*BS_)
#define US_BASE_FLOATS (68*BS_ + 16)
// ushort-region offsets (in ushorts, from usb)
#define US_XB 0
#define US_QB (BS_*64)     // q for k4; reused as bf16 pe_event for k5
#define US_KB (2*BS_*64)   // k for k4; reused as bf16 w_proj for k5
#define US_XT (3*BS_*64)

#define MFMA16(a,b,c) __builtin_amdgcn_mfma_f32_16x16x32_bf16(a,b,c,0,0,0)

__device__ __forceinline__ u16 f2bf(float f){
  unsigned u = __float_as_uint(f);
  return (u16)((u + 0x7FFFu + ((u>>16)&1u)) >> 16);
}
// f32-tile swizzle used by k1
__device__ __forceinline__ int swz_phys(int row, int c){ return row*64 + (((c ^ (row & 15))) << 2); }

// K1: q/k (fp32 compute -> bf16 store), sq, rel sums, xb16, xT16
__global__ __launch_bounds__(256) void k1_prep(
    const float* __restrict__ x, const float* __restrict__ wq, const float* __restrict__ bq,
    const float* __restrict__ wk, const float* __restrict__ bk,
    const float* __restrict__ scale_w, float* __restrict__ ws, u16* __restrict__ usb)
{
  __shared__ __align__(16) float xl[16*68];
  __shared__ __align__(16) float wql[4096];
  __shared__ __align__(16) float wkl[4096];
  int tid = threadIdx.x, lane = tid & 63, wv = tid >> 6;
  int row0 = blockIdx.x * 16;
  {
    int r = tid >> 4, c = tid & 15;
    *(float4*)(xl + r*68 + c*4) = *(const float4*)(x + (size_t)(row0 + r)*F_ + c*4);
  }
  for (int i = 0; i < 4; ++i){
    int idx = tid + i*256;
    int g = idx >> 4, c = idx & 15;
    float4 v = *(const float4*)(wq + g*F_ + c*4);
    int pb = swz_phys(g, c);
    wql[pb]=v.x; wql[pb+1]=v.y; wql[pb+2]=v.z; wql[pb+3]=v.w;
    float4 u = *(const float4*)(wk + g*F_ + c*4);
    wkl[pb]=u.x; wkl[pb+1]=u.y; wkl[pb+2]=u.z; wkl[pb+3]=u.w;
  }
  __syncthreads();
  int g = lane;
  int swl = g & 15;
  float qa[4], ka[4];
  #pragma unroll
  for (int j=0;j<4;++j){ qa[j]=bq[g]; ka[j]=bk[g]; }
  #pragma unroll
  for (int c=0;c<16;++c){
    float4 wqv = *(const float4*)(wql + g*64 + ((c ^ swl)<<2));
    float4 wkv = *(const float4*)(wkl + g*64 + ((c ^ swl)<<2));
    #pragma unroll
    for (int j=0;j<4;++j){
      float4 xv = *(const float4*)(xl + (wv*4+j)*68 + c*4);
      qa[j] += xv.x*wqv.x + xv.y*wqv.y + xv.z*wqv.z + xv.w*wqv.w;
      ka[j] += xv.x*wkv.x + xv.y*wkv.y + xv.z*wkv.z + xv.w*wkv.w;
    }
  }
  #pragma unroll
  for (int j=0;j<4;++j){
    int rg = row0 + wv*4 + j;
    usb[US_QB + (size_t)rg*64 + g] = f2bf(qa[j]);
    usb[US_KB + (size_t)rg*64 + g] = f2bf(ka[j]);
  }
  #pragma unroll
  for (int j=0;j<4;++j){
    int r = wv*4 + j;
    float v = xl[r*68 + lane];
    float s = v*v;
    for (int o=32;o;o>>=1) s += __shfl_xor(s, o, 64);
    if (lane == 0) ws[WS_SQ + row0 + r] = s;
  }
  #pragma unroll
  for (int j=0;j<4;++j){
    int r = wv*4 + j;
    int rg = row0 + r;
    int b = rg >> 11, s_loc = rg & (S_-1);
    float d0 = xl[r*68 + 0], e0 = xl[r*68 + 1];
    float dd = 0.f, de = 0.f, wd = 0.f;
    int n = lane + 1;
    if (lane < NS_ && s_loc >= n){
      const float* xp = x + ((size_t)(b*S_ + s_loc - n))*F_;
      float dp_ = xp[0], ep = xp[1];
      dd = dp_ - d0;
      de = ep - e0;
      wd = scale_w[lane] * __expf(-fabsf(dd) * (1.0f/(float)(1<<n)));
    }
    for (int o=4;o;o>>=1){
      dd += __shfl_down(dd, o, 64);
      de += __shfl_down(de, o, 64);
      wd += __shfl_down(wd, o, 64);
    }
    if (lane == 0){
      ws[WS_REL + rg*3+0] = dd;
      ws[WS_REL + rg*3+1] = de;
      ws[WS_REL + rg*3+2] = wd;
    }
  }
  // bf16 x (row-major)
  {
    int r = tid >> 4, cb = (tid & 15)*4;
    unsigned w0 = (unsigned)f2bf(xl[r*68+cb])   | ((unsigned)f2bf(xl[r*68+cb+1])<<16);
    unsigned w1 = (unsigned)f2bf(xl[r*68+cb+2]) | ((unsigned)f2bf(xl[r*68+cb+3])<<16);
    uint2 pk; pk.x = w0; pk.y = w1;
    *(uint2*)(usb + US_XB + (size_t)(row0+r)*64 + cb) = pk;
  }
  // bf16 x transposed per batch: xT[b][f][t]
  {
    int f = tid & 63, rg4 = (tid >> 6)*4;
    unsigned wa = (unsigned)f2bf(xl[(rg4+0)*68+f]) | ((unsigned)f2bf(xl[(rg4+1)*68+f])<<16);
    unsigned wb = (unsigned)f2bf(xl[(rg4+2)*68+f]) | ((unsigned)f2bf(xl[(rg4+3)*68+f])<<16);
    uint2 pk; pk.x = wa; pk.y = wb;
    int bb = row0 >> 11;
    int tloc = (row0 & (S_-1)) + rg4;
    *(uint2*)(usb + US_XT + (size_t)bb*64*2048 + (size_t)f*2048 + tloc) = pk;
  }
}

// K2: euclid stats via MFMA Gram, upper-triangle tiles only (off-diag weight 2).
// Per-block partials -> WS_PE region (consumed by k3 before k4 overwrites).
__global__ __launch_bounds__(256) void k2_stats(const u16* __restrict__ us, float* __restrict__ ws)
{
  __shared__ __align__(16) u16 Xls[4096];
  __shared__ float sqs_l[64], sqt_l[64];
  __shared__ float rsum[4], rss[4], rmn[4], rmx[4];
  int tid = threadIdx.x, lane = tid & 63, wv = tid >> 6;
  int lg = lane >> 4, lc = lane & 15;
  int b = blockIdx.y;
  int rem = blockIdx.x, i = 0;
  while (rem >= 32 - i){ rem -= 32 - i; ++i; }
  int j = i + rem;
  int s0 = i*64, t0 = j*64;
  size_t rb = (size_t)b * S_;
  const u16* xb = us + US_XB;
  #pragma unroll
  for (int p2=0;p2<2;++p2){
    int slot = tid + p2*256;
    int row = slot>>3, pc = slot&7, lcn = pc ^ (row&7);
    ((short8*)Xls)[slot] = *(const short8*)(xb + (rb + t0 + row)*64 + lcn*8);
  }
  if (tid < 64) sqs_l[tid] = ws[WS_SQ + rb + s0 + tid];
  else if (tid < 128) sqt_l[tid-64] = ws[WS_SQ + rb + t0 + (tid-64)];
  short8 a0 = *(const short8*)(xb + (rb + s0 + wv*16 + lc)*64 + lg*8);
  short8 a1 = *(const short8*)(xb + (rb + s0 + wv*16 + lc)*64 + 32 + lg*8);
  __syncthreads();
  f32x4 acc[4];
  #pragma unroll
  for (int t=0;t<4;++t){ acc[t][0]=0.f; acc[t][1]=0.f; acc[t][2]=0.f; acc[t][3]=0.f; }
  #pragma unroll
  for (int ts=0; ts<4; ++ts){
    int rowb = ts*16 + lc;
    int sw = rowb & 7;
    short8 b0 = *(const short8*)(Xls + rowb*64 + ((lg ^ sw)<<3));
    short8 b1 = *(const short8*)(Xls + rowb*64 + (((4+lg) ^ sw)<<3));
    acc[ts] = MFMA16(a0, b0, acc[ts]);
    acc[ts] = MFMA16(a1, b1, acc[ts]);
  }
  float sq_s[4];
  #pragma unroll
  for (int r=0;r<4;++r) sq_s[r] = sqs_l[wv*16 + lg*4 + r];
  float lsum=0.f, lss=0.f, lmn=3.4e38f, lmx=-3.4e38f;
  #pragma unroll
  for (int ts=0; ts<4; ++ts){
    float sqt = sqt_l[ts*16 + lc];
    #pragma unroll
    for (int r=0;r<4;++r){
      float gg = acc[ts][r];
      float d2 = sq_s[r] + sqt - 2.f*gg;
      d2 = fmaxf(d2, 0.f);
      float eu = d2 > 0.f ? sqrtf(d2) : 0.f;
      lsum += eu; lss += eu*eu;
      lmn = fminf(lmn, eu); lmx = fmaxf(lmx, eu);
    }
  }
  for (int o=32;o;o>>=1){
    lsum += __shfl_xor(lsum, o, 64);
    lss  += __shfl_xor(lss, o, 64);
    lmn = fminf(lmn, __shfl_xor(lmn, o, 64));
    lmx = fmaxf(lmx, __shfl_xor(lmx, o, 64));
  }
  if (lane == 0){ rsum[wv]=lsum; rss[wv]=lss; rmn[wv]=lmn; rmx[wv]=lmx; }
  __syncthreads();
  if (tid == 0){
    float bs=0.f, bss=0.f, bmn=3.4e38f, bmx=-3.4e38f;
    for (int w2=0;w2<4;++w2){ bs+=rsum[w2]; bss+=rss[w2]; bmn=fminf(bmn,rmn[w2]); bmx=fmaxf(bmx,rmx[w2]); }
    float wgt = (i==j) ? 1.f : 2.f;
    float* part = ws + WS_PE;
    int bid = blockIdx.y * NTILE_ + blockIdx.x;
    part[bid]           = bs*wgt;
    part[NPART_ + bid]  = bss*wgt;
    part[2*NPART_ + bid]= bmn;
    part[3*NPART_ + bid]= bmx;
  }
}

// K3: reduce k2 partials + finalize scalar params
__global__ __launch_bounds__(256) void k3_fin(const float* __restrict__ alpha,
                                              const float* __restrict__ sigma_w, float* ws){
  __shared__ double ssm[256], sss[256];
  __shared__ float smn[256], smx[256];
  int tid = threadIdx.x;
  const float* part = ws + WS_PE;
  double s = 0.0, ss = 0.0;
  float mn = 3.4e38f, mx = -3.4e38f;
  for (int i2 = tid; i2 < NPART_; i2 += 256){
    s  += (double)part[i2];
    ss += (double)part[NPART_ + i2];
    mn = fminf(mn, part[2*NPART_ + i2]);
    mx = fmaxf(mx, part[3*NPART_ + i2]);
  }
  ssm[tid]=s; sss[tid]=ss; smn[tid]=mn; smx[tid]=mx;
  __syncthreads();
  for (int st = 128; st; st >>= 1){
    if (tid < st){
      ssm[tid] += ssm[tid+st];
      sss[tid] += sss[tid+st];
      smn[tid] = fminf(smn[tid], smn[tid+st]);
      smx[tid] = fmaxf(smx[tid], smx[tid+st]);
    }
    __syncthreads();
  }
  if (tid == 0){
    double N = (double)B_*S_*S_;
    double sum = ssm[0], sumsq = sss[0];
    double mean = sum/N;
    double var  = (sumsq - sum*sum/N) / (N - 1.0);
    float stdv = (float)sqrt(fmax(var, 0.0));
    float m = (float)mean;
    float lo = m - 2.f*stdv, hi = m + 2.f*stdv;
    float cmn = fminf(fmaxf(smn[0], lo), hi);
    float cmx = fminf(fmaxf(smx[0], lo), hi);
    float invr = 1.f/(cmx - cmn + 1e-6f);
    float a = 1.f/(1.f + expf(-alpha[0]));
    float swv = sigma_w[0];
    float sp = (swv > 20.f) ? swv : log1pf(expf(swv));
    float sg = sp + 0.001f;
    float efac = -0.5f/(sg*sg);
    float* p = ws + WS_STATS + 8;
    p[0]=lo; p[1]=hi; p[2]=cmn; p[3]=invr; p[4]=a; p[5]=1.f-a; p[6]=efac;
  }
}

// K4: MFMA flash pass — R5 structure (8 waves, s-tile 64) with online max REMOVED:
// scores bounded, fixed -8 shift cancels in pe/z ratio. 2 barriers per tile.
__global__ __launch_bounds__(512) void k4_flash(const u16* __restrict__ us, float* __restrict__ ws)
{
  __shared__ __align__(16) u16 SMEM[16384];  // Kls|Xls|XTls|el : 4x8KB
  __shared__ float sqt_l[64], invt_l[64];
  __shared__ float zb[4][2][16];
  u16* Kls  = SMEM;
  u16* Xls  = SMEM + 4096;
  u16* XTls = SMEM + 8192;
  u16* elp  = SMEM + 12288;
  int tid = threadIdx.x, lane = tid & 63, wv = tid >> 6;
  int lg = lane >> 4, lc = lane & 15;
  int ssub = wv >> 1, th = wv & 1;
  int b = blockIdx.y;
  size_t rb = (size_t)b * S_;
  int s0 = blockIdx.x * 64;
  const u16* xb = us + US_XB;
  const u16* qb = us + US_QB;
  const u16* kb = us + US_KB;
  const u16* xt = us + US_XT + (size_t)b*64*2048;
  int srow = s0 + ssub*16 + lc;
  short8 qf0 = *(const short8*)(qb + (rb+srow)*64 + lg*8);
  short8 qf1 = *(const short8*)(qb + (rb+srow)*64 + 32 + lg*8);
  short8 xf0 = *(const short8*)(xb + (rb+srow)*64 + lg*8);
  short8 xf1 = *(const short8*)(xb + (rb+srow)*64 + 32 + lg*8);
  float sq_s[4], inv_s[4];
  #pragma unroll
  for (int r=0;r<4;++r){
    float s = ws[WS_SQ + rb + s0 + ssub*16 + lg*4 + r];
    sq_s[r] = s; inv_s[r] = 1.f / fmaxf(sqrtf(s), 1e-12f);
  }
  const float* prm = ws + WS_STATS + 8;
  float lo=prm[0], hi=prm[1], cmn=prm[2], invr=prm[3], a=prm[4], oma=prm[5], efac=prm[6];
  f32x4 pe[4];
  #pragma unroll
  for (int t=0;t<4;++t){ pe[t][0]=0.f; pe[t][1]=0.f; pe[t][2]=0.f; pe[t][3]=0.f; }
  float zrun[4];
  #pragma unroll
  for (int r=0;r<4;++r) zrun[r]=0.f;

  for (int t0 = 0; t0 < S_; t0 += 64){
    {
      int slot = tid;
      int row = slot>>3, pc = slot&7, lcn = pc ^ (row&7);
      ((short8*)Kls)[slot]  = *(const short8*)(kb + (rb + t0 + row)*64 + lcn*8);
      ((short8*)Xls)[slot]  = *(const short8*)(xb + (rb + t0 + row)*64 + lcn*8);
      ((short8*)XTls)[slot] = *(const short8*)(xt + (size_t)row*2048 + t0 + lcn*8);
    }
    if (tid < 64){
      float s = ws[WS_SQ + rb + t0 + tid];
      sqt_l[tid] = s;
      invt_l[tid] = 1.f / fmaxf(sqrtf(s), 1e-12f);
    }
    __syncthreads();
    f32x4 ga[2], sa[2];
    #pragma unroll
    for (int t=0;t<2;++t){ ga[t][0]=0.f; ga[t][1]=0.f; ga[t][2]=0.f; ga[t][3]=0.f;
                           sa[t][0]=0.f; sa[t][1]=0.f; sa[t][2]=0.f; sa[t][3]=0.f; }
    #pragma unroll
    for (int ts=0; ts<2; ++ts){
      int rowb = (2*th+ts)*16 + lc;
      int sw = rowb & 7;
      short8 bk0 = *(const short8*)(Kls + rowb*64 + ((lg ^ sw)<<3));
      short8 bx0 = *(const short8*)(Xls + rowb*64 + ((lg ^ sw)<<3));
      sa[ts] = MFMA16(qf0, bk0, sa[ts]);
      ga[ts] = MFMA16(xf0, bx0, ga[ts]);
      short8 bk1 = *(const short8*)(Kls + rowb*64 + (((4+lg) ^ sw)<<3));
      short8 bx1 = *(const short8*)(Xls + rowb*64 + (((4+lg) ^ sw)<<3));
      sa[ts] = MFMA16(qf1, bk1, sa[ts]);
      ga[ts] = MFMA16(xf1, bx1, ga[ts]);
    }
    #pragma unroll
    for (int ts=0; ts<2; ++ts){
      int col = (2*th+ts)*16 + lc;
      float sqt = sqt_l[col], invt = invt_l[col];
      #pragma unroll
      for (int r=0;r<4;++r){
        float gg = ga[ts][r];
        float cosv = (gg*inv_s[r]*invt + 1.f)*0.5f;
        float d2 = sq_s[r] + sqt - 2.f*gg;
        d2 = fmaxf(d2, 0.f);
        float eu = d2 > 0.f ? sqrtf(d2) : 0.f;
        eu = fminf(fmaxf(eu, lo), hi);
        float en = (eu - cmn)*invr;
        float hyb = a*cosv + oma*(1.f - en);
        float H = __expf(hyb*efac);
        float p = __expf(__builtin_fmaf(sa[ts][r], 0.125f, -8.f));
        zrun[r] += p;
        int rowl = lg*4 + r;
        int phys = rowl*64 + ((((col>>3) ^ (rowl&7)))<<3) + (col&7);
        elp[ssub*1024 + phys] = f2bf(p*H);
      }
    }
    // PV: pe[fs] += E(16x32 window) @ x(32 x 16f)
    {
      int swA = lc & 7;
      short8 Ae = *(const short8*)(elp + ssub*1024 + lc*64 + (((4*th + lg) ^ swA)<<3));
      #pragma unroll
      for (int fs=0; fs<4; ++fs){
        int rowf = fs*16 + lc;
        short8 Bx = *(const short8*)(XTls + rowf*64 + (((4*th + lg) ^ (rowf&7))<<3));
        pe[fs] = MFMA16(Ae, Bx, pe[fs]);
      }
    }
    __syncthreads();
  }
  // z reduce + cross-half combine
  #pragma unroll
  for (int r=0;r<4;++r){
    float z = zrun[r];
    z += __shfl_xor(z, 1, 64);
    z += __shfl_xor(z, 2, 64);
    z += __shfl_xor(z, 4, 64);
    z += __shfl_xor(z, 8, 64);
    if (lc == r) zb[ssub][th][lg*4+r] = z;
  }
  __syncthreads();
  float* tmp = (float*)SMEM;  // 4096 floats scratch (tiles dead now)
  if (th == 1){
    #pragma unroll
    for (int fs=0; fs<4; ++fs)
      #pragma unroll
      for (int r=0;r<4;++r)
        tmp[ssub*1024 + (lg*4+r)*64 + fs*16 + lc] = pe[fs][r];
  }
  __syncthreads();
  if (th == 0){
    float zi[4];
    #pragma unroll
    for (int r=0;r<4;++r) zi[r] = 1.f / (zb[ssub][0][lg*4+r] + zb[ssub][1][lg*4+r]);
    #pragma unroll
    for (int fs=0; fs<4; ++fs)
      #pragma unroll
      for (int r=0;r<4;++r){
        float v = pe[fs][r] + tmp[ssub*1024 + (lg*4+r)*64 + fs*16 + lc];
        ws[WS_PE + (rb + s0 + ssub*16 + lg*4 + r)*64 + fs*16 + lc] = v * zi[r];
      }
  }
}

// KPE: convert f32 pe_event (WS_PE) -> bf16 into US_QB (q dead after k4)
__global__ __launch_bounds__(256) void kpe_conv(const float* __restrict__ pef, u16* __restrict__ usb){
  size_t i = ((size_t)blockIdx.x*256 + threadIdx.x)*4;
  float4 v = *(const float4*)(pef + i);
  uint2 pk;
  pk.x = (unsigned)f2bf(v.x) | ((unsigned)f2bf(v.y)<<16);
  pk.y = (unsigned)f2bf(v.z) | ((unsigned)f2bf(v.w)<<16);
  *(uint2*)(usb + US_QB + i) = pk;
}

// KW: convert w_proj (512x64 f32) -> bf16 into US_KB (k dead after k4)
__global__ __launch_bounds__(256) void kw_conv(const float* __restrict__ wp, u16* __restrict__ usb){
  int i = (blockIdx.x*256 + threadIdx.x)*4;
  float4 v = *(const float4*)(wp + i);
  uint2 pk;
  pk.x = (unsigned)f2bf(v.x) | ((unsigned)f2bf(v.y)<<16);
  pk.y = (unsigned)f2bf(v.z) | ((unsigned)f2bf(v.w)<<16);
  *(uint2*)(usb + US_KB + i) = pk;
}

// K5: pe_proj via MFMA (bf16 pe @ bf16 w_proj, both from L2 via clean u16* param)
//     + both LayerNorms + add
__global__ __launch_bounds__(256) void k5_final(
    const float* __restrict__ w_rel, const float* __restrict__ b_rel,
    const float* __restrict__ b_proj,
    const float* __restrict__ g1, const float* __restrict__ bt1,
    const float* __restrict__ g2, const float* __restrict__ bt2,
    const float* __restrict__ ws, const u16* __restrict__ usb, float* __restrict__ out)
{
  __shared__ __align__(16) float res[16*512];
  __shared__ float rsl[48];
  __shared__ float g1l[512], b1l[512], g2l[512], b2l[512], brl[512], wrl[1536];
  int tid = threadIdx.x, lane = tid & 63, wv = tid >> 6;
  int lg = lane >> 4, lc = lane & 15;
  int row0 = blockIdx.x * 16;
  const u16* peb = usb + US_QB;
  const u16* wb  = usb + US_KB;
  short8 a0 = *(const short8*)(peb + (size_t)(row0+lc)*64 + lg*8);
  short8 a1 = *(const short8*)(peb + (size_t)(row0+lc)*64 + 32 + lg*8);
  if (tid < 48) rsl[tid] = ws[WS_REL + row0*3 + tid];
  for (int i = tid; i < 512; i += 256){
    g1l[i]=g1[i]; b1l[i]=bt1[i]; g2l[i]=g2[i]; b2l[i]=bt2[i]; brl[i]=b_rel[i];
  }
  for (int i = tid; i < 1536; i += 256) wrl[i] = w_rel[i];
  int wc0 = wv*128;
  #pragma unroll
  for (int cg=0; cg<8; ++cg){
    int d = wc0 + cg*16 + lc;
    short8 b0 = *(const short8*)(wb + (size_t)d*64 + lg*8);
    short8 b1 = *(const short8*)(wb + (size_t)d*64 + 32 + lg*8);
    f32x4 acc = {0.f,0.f,0.f,0.f};
    acc = MFMA16(a0, b0, acc);
    acc = MFMA16(a1, b1, acc);
    float bp = b_proj[d];
    #pragma unroll
    for (int r=0;r<4;++r) res[(lg*4+r)*512 + d] = acc[r] + bp;
  }
  __syncthreads();
  #pragma unroll
  for (int j=0;j<4;++j){
    int r = wv*4 + j;
    int rg = row0 + r;
    float s1=0.f, q1=0.f;
    float vals[8];
    #pragma unroll
    for (int i=0;i<8;++i){ float v = res[r*512 + i*64 + lane]; vals[i]=v; s1+=v; q1+=v*v; }
    for (int o=32;o;o>>=1){ s1 += __shfl_xor(s1,o,64); q1 += __shfl_xor(q1,o,64); }
    float mu1 = s1*(1.f/512.f);
    float var1 = q1*(1.f/512.f) - mu1*mu1;
    float rsg1 = rsqrtf(fmaxf(var1, 0.f) + 1e-5f);
    float c0 = rsl[r*3+0], c1 = rsl[r*3+1], c2 = rsl[r*3+2];
    float rv[8]; float s2=0.f, q2=0.f;
    #pragma unroll
    for (int i=0;i<8;++i){
      int d = i*64 + lane;
      float v = c0*wrl[d*3+0] + c1*wrl[d*3+1] + c2*wrl[d*3+2] + 5.f*brl[d];
      rv[i]=v; s2+=v; q2+=v*v;
    }
    for (int o=32;o;o>>=1){ s2 += __shfl_xor(s2,o,64); q2 += __shfl_xor(q2,o,64); }
    float mu2 = s2*(1.f/512.f);
    float var2 = q2*(1.f/512.f) - mu2*mu2;
    float rsg2 = rsqrtf(fmaxf(var2, 0.f) + 1e-5f);
    #pragma unroll
    for (int i=0;i<8;++i){
      int d = i*64 + lane;
      float o1 = (vals[i]-mu1)*rsg1*g2l[d] + b2l[d];
      float o2 = (rv[i]-mu2)*rsg2*g1l[d] + b1l[d];
      out[(size_t)rg*512 + d] = o1 + o2;
    }
  }
}

extern "C" void kernel_launch(void* const* d_in, const int* in_sizes, int n_in,
                              void* d_out, int out_size, void* d_ws, size_t ws_size,
                              hipStream_t stream)
{
  const float* x      = (const float*)d_in[0];
  const float* w_rel  = (const float*)d_in[1];
  const float* b_rel  = (const float*)d_in[2];
  const float* w_proj = (const float*)d_in[3];
  const float* b_proj = (const float*)d_in[4];
  const float* g1     = (const float*)d_in[5];
  const float* bt1    = (const float*)d_in[6];
  const float* g2     = (const float*)d_in[7];
  const float* bt2    = (const float*)d_in[8];
  const float* alpha  = (const float*)d_in[9];
  const float* sigma_w= (const float*)d_in[10];
  const float* wq     = (const float*)d_in[11];
  const float* bq     = (const float*)d_in[12];
  const float* wk     = (const float*)d_in[13];
  const float* bk     = (const float*)d_in[14];
  const float* scale_w= (const float*)d_in[15];
  float* wsf = (float*)d_ws;
  u16*  usb = (u16*)(wsf + US_BASE_FLOATS);
  float* out = (float*)d_out;

  hipLaunchKernelGGL(k1_prep, dim3(BS_/16), dim3(256), 0, stream, x, wq, bq, wk, bk, scale_w, wsf, usb);
  hipLaunchKernelGGL(k2_stats, dim3(NTILE_, B_), dim3(256), 0, stream, usb, wsf);
  hipLaunchKernelGGL(k3_fin, dim3(1), dim3(256), 0, stream, alpha, sigma_w, wsf);
  hipLaunchKernelGGL(k4_flash, dim3(S_/64, B_), dim3(512), 0, stream, usb, wsf);
  hipLaunchKernelGGL(kpe_conv, dim3(BS_*64/1024), dim3(256), 0, stream, wsf + WS_PE, usb);
  hipLaunchKernelGGL(kw_conv, dim3(32), dim3(256), 0, stream, w_proj, usb);
  hipLaunchKernelGGL(k5_final, dim3(BS_/16), dim3(256), 0, stream,
                     w_rel, b_rel, b_proj, g1, bt1, g2, bt2, wsf, usb, out);
}

// Round 7
// 216.724 us; speedup vs baseline: 5.5227x; 1.0444x over previous
//
#include <hip/hip_runtime.h>
#include <math.h>

#define B_ 8
#define S_ 2048
#define F_ 64
#define D_ 512
#define NS_ 5
#define BS_ (B_*S_)
#define NTILE_ 528
#define NPART_ (NTILE_*B_)

typedef unsigned short u16;
typedef __attribute__((ext_vector_type(8))) short short8;
typedef __attribute__((ext_vector_type(4))) float f32x4;

// float-region offsets (in floats)
#define WS_SQ    0
#define WS_REL   (BS_)
#define WS_PE    (4*BS_)       // k2 partials [0,16896); bf16 w_proj at +20480 (u16 view)
#define WS_WPB   (WS_PE + 20480)
#define WS_STATS (68*BS_)
#define US_BASE_FLOATS (68*BS_ + 16)
// ushort-region offsets (in ushorts, from usb)
#define US_XB 0
#define US_QB (BS_*64)     // q for k4; k4 overwrites in-place with bf16 pe_event for k5
#define US_KB (2*BS_*64)
#define US_XT (3*BS_*64)

#define MFMA16(a,b,c) __builtin_amdgcn_mfma_f32_16x16x32_bf16(a,b,c,0,0,0)

__device__ __forceinline__ u16 f2bf(float f){
  unsigned u = __float_as_uint(f);
  return (u16)((u + 0x7FFFu + ((u>>16)&1u)) >> 16);
}
// f32-tile swizzle used by k1
__device__ __forceinline__ int swz_phys(int row, int c){ return row*64 + (((c ^ (row & 15))) << 2); }

// K1: q/k (fp32 compute -> bf16 store), sq, rel sums, xb16, xT16, w_proj bf16 (blocks 0..31)
__global__ __launch_bounds__(256) void k1_prep(
    const float* __restrict__ x, const float* __restrict__ wq, const float* __restrict__ bq,
    const float* __restrict__ wk, const float* __restrict__ bk,
    const float* __restrict__ scale_w, const float* __restrict__ wp,
    float* __restrict__ ws, u16* __restrict__ usb, u16* __restrict__ wpb)
{
  __shared__ __align__(16) float xl[16*68];
  __shared__ __align__(16) float wql[4096];
  __shared__ __align__(16) float wkl[4096];
  int tid = threadIdx.x, lane = tid & 63, wv = tid >> 6;
  int row0 = blockIdx.x * 16;
  {
    int r = tid >> 4, c = tid & 15;
    *(float4*)(xl + r*68 + c*4) = *(const float4*)(x + (size_t)(row0 + r)*F_ + c*4);
  }
  for (int i = 0; i < 4; ++i){
    int idx = tid + i*256;
    int g = idx >> 4, c = idx & 15;
    float4 v = *(const float4*)(wq + g*F_ + c*4);
    int pb = swz_phys(g, c);
    wql[pb]=v.x; wql[pb+1]=v.y; wql[pb+2]=v.z; wql[pb+3]=v.w;
    float4 u = *(const float4*)(wk + g*F_ + c*4);
    wkl[pb]=u.x; wkl[pb+1]=u.y; wkl[pb+2]=u.z; wkl[pb+3]=u.w;
  }
  // w_proj bf16 conversion (independent work, blocks 0..31)
  if (blockIdx.x < 32){
    int i2 = (blockIdx.x*256 + tid)*4;
    float4 v = *(const float4*)(wp + i2);
    uint2 pk2;
    pk2.x = (unsigned)f2bf(v.x) | ((unsigned)f2bf(v.y)<<16);
    pk2.y = (unsigned)f2bf(v.z) | ((unsigned)f2bf(v.w)<<16);
    *(uint2*)(wpb + i2) = pk2;
  }
  __syncthreads();
  int g = lane;
  int swl = g & 15;
  float qa[4], ka[4];
  #pragma unroll
  for (int j=0;j<4;++j){ qa[j]=bq[g]; ka[j]=bk[g]; }
  #pragma unroll
  for (int c=0;c<16;++c){
    float4 wqv = *(const float4*)(wql + g*64 + ((c ^ swl)<<2));
    float4 wkv = *(const float4*)(wkl + g*64 + ((c ^ swl)<<2));
    #pragma unroll
    for (int j=0;j<4;++j){
      float4 xv = *(const float4*)(xl + (wv*4+j)*68 + c*4);
      qa[j] += xv.x*wqv.x + xv.y*wqv.y + xv.z*wqv.z + xv.w*wqv.w;
      ka[j] += xv.x*wkv.x + xv.y*wkv.y + xv.z*wkv.z + xv.w*wkv.w;
    }
  }
  #pragma unroll
  for (int j=0;j<4;++j){
    int rg = row0 + wv*4 + j;
    usb[US_QB + (size_t)rg*64 + g] = f2bf(qa[j]);
    usb[US_KB + (size_t)rg*64 + g] = f2bf(ka[j]);
  }
  #pragma unroll
  for (int j=0;j<4;++j){
    int r = wv*4 + j;
    float v = xl[r*68 + lane];
    float s = v*v;
    for (int o=32;o;o>>=1) s += __shfl_xor(s, o, 64);
    if (lane == 0) ws[WS_SQ + row0 + r] = s;
  }
  #pragma unroll
  for (int j=0;j<4;++j){
    int r = wv*4 + j;
    int rg = row0 + r;
    int b = rg >> 11, s_loc = rg & (S_-1);
    float d0 = xl[r*68 + 0], e0 = xl[r*68 + 1];
    float dd = 0.f, de = 0.f, wd = 0.f;
    int n = lane + 1;
    if (lane < NS_ && s_loc >= n){
      const float* xp = x + ((size_t)(b*S_ + s_loc - n))*F_;
      float dp_ = xp[0], ep = xp[1];
      dd = dp_ - d0;
      de = ep - e0;
      wd = scale_w[lane] * __expf(-fabsf(dd) * (1.0f/(float)(1<<n)));
    }
    for (int o=4;o;o>>=1){
      dd += __shfl_down(dd, o, 64);
      de += __shfl_down(de, o, 64);
      wd += __shfl_down(wd, o, 64);
    }
    if (lane == 0){
      ws[WS_REL + rg*3+0] = dd;
      ws[WS_REL + rg*3+1] = de;
      ws[WS_REL + rg*3+2] = wd;
    }
  }
  // bf16 x (row-major)
  {
    int r = tid >> 4, cb = (tid & 15)*4;
    unsigned w0 = (unsigned)f2bf(xl[r*68+cb])   | ((unsigned)f2bf(xl[r*68+cb+1])<<16);
    unsigned w1 = (unsigned)f2bf(xl[r*68+cb+2]) | ((unsigned)f2bf(xl[r*68+cb+3])<<16);
    uint2 pk; pk.x = w0; pk.y = w1;
    *(uint2*)(usb + US_XB + (size_t)(row0+r)*64 + cb) = pk;
  }
  // bf16 x transposed per batch: xT[b][f][t]
  {
    int f = tid & 63, rg4 = (tid >> 6)*4;
    unsigned wa = (unsigned)f2bf(xl[(rg4+0)*68+f]) | ((unsigned)f2bf(xl[(rg4+1)*68+f])<<16);
    unsigned wb = (unsigned)f2bf(xl[(rg4+2)*68+f]) | ((unsigned)f2bf(xl[(rg4+3)*68+f])<<16);
    uint2 pk; pk.x = wa; pk.y = wb;
    int bb = row0 >> 11;
    int tloc = (row0 & (S_-1)) + rg4;
    *(uint2*)(usb + US_XT + (size_t)bb*64*2048 + (size_t)f*2048 + tloc) = pk;
  }
}

// K2: euclid stats via MFMA Gram, upper-triangle tiles only (off-diag weight 2).
// Per-block partials -> WS_PE region (consumed by k3).
__global__ __launch_bounds__(256) void k2_stats(const u16* __restrict__ us, float* __restrict__ ws)
{
  __shared__ __align__(16) u16 Xls[4096];
  __shared__ float sqs_l[64], sqt_l[64];
  __shared__ float rsum[4], rss[4], rmn[4], rmx[4];
  int tid = threadIdx.x, lane = tid & 63, wv = tid >> 6;
  int lg = lane >> 4, lc = lane & 15;
  int b = blockIdx.y;
  int rem = blockIdx.x, i = 0;
  while (rem >= 32 - i){ rem -= 32 - i; ++i; }
  int j = i + rem;
  int s0 = i*64, t0 = j*64;
  size_t rb = (size_t)b * S_;
  const u16* xb = us + US_XB;
  #pragma unroll
  for (int p2=0;p2<2;++p2){
    int slot = tid + p2*256;
    int row = slot>>3, pc = slot&7, lcn = pc ^ (row&7);
    ((short8*)Xls)[slot] = *(const short8*)(xb + (rb + t0 + row)*64 + lcn*8);
  }
  if (tid < 64) sqs_l[tid] = ws[WS_SQ + rb + s0 + tid];
  else if (tid < 128) sqt_l[tid-64] = ws[WS_SQ + rb + t0 + (tid-64)];
  short8 a0 = *(const short8*)(xb + (rb + s0 + wv*16 + lc)*64 + lg*8);
  short8 a1 = *(const short8*)(xb + (rb + s0 + wv*16 + lc)*64 + 32 + lg*8);
  __syncthreads();
  f32x4 acc[4];
  #pragma unroll
  for (int t=0;t<4;++t){ acc[t][0]=0.f; acc[t][1]=0.f; acc[t][2]=0.f; acc[t][3]=0.f; }
  #pragma unroll
  for (int ts=0; ts<4; ++ts){
    int rowb = ts*16 + lc;
    int sw = rowb & 7;
    short8 b0 = *(const short8*)(Xls + rowb*64 + ((lg ^ sw)<<3));
    short8 b1 = *(const short8*)(Xls + rowb*64 + (((4+lg) ^ sw)<<3));
    acc[ts] = MFMA16(a0, b0, acc[ts]);
    acc[ts] = MFMA16(a1, b1, acc[ts]);
  }
  float sq_s[4];
  #pragma unroll
  for (int r=0;r<4;++r) sq_s[r] = sqs_l[wv*16 + lg*4 + r];
  float lsum=0.f, lss=0.f, lmn=3.4e38f, lmx=-3.4e38f;
  #pragma unroll
  for (int ts=0; ts<4; ++ts){
    float sqt = sqt_l[ts*16 + lc];
    #pragma unroll
    for (int r=0;r<4;++r){
      float gg = acc[ts][r];
      float d2 = sq_s[r] + sqt - 2.f*gg;
      d2 = fmaxf(d2, 0.f);
      float eu = d2 > 0.f ? sqrtf(d2) : 0.f;
      lsum += eu; lss += eu*eu;
      lmn = fminf(lmn, eu); lmx = fmaxf(lmx, eu);
    }
  }
  for (int o=32;o;o>>=1){
    lsum += __shfl_xor(lsum, o, 64);
    lss  += __shfl_xor(lss, o, 64);
    lmn = fminf(lmn, __shfl_xor(lmn, o, 64));
    lmx = fmaxf(lmx, __shfl_xor(lmx, o, 64));
  }
  if (lane == 0){ rsum[wv]=lsum; rss[wv]=lss; rmn[wv]=lmn; rmx[wv]=lmx; }
  __syncthreads();
  if (tid == 0){
    float bs=0.f, bss=0.f, bmn=3.4e38f, bmx=-3.4e38f;
    for (int w2=0;w2<4;++w2){ bs+=rsum[w2]; bss+=rss[w2]; bmn=fminf(bmn,rmn[w2]); bmx=fmaxf(bmx,rmx[w2]); }
    float wgt = (i==j) ? 1.f : 2.f;
    float* part = ws + WS_PE;
    int bid = blockIdx.y * NTILE_ + blockIdx.x;
    part[bid]           = bs*wgt;
    part[NPART_ + bid]  = bss*wgt;
    part[2*NPART_ + bid]= bmn;
    part[3*NPART_ + bid]= bmx;
  }
}

// K3: reduce k2 partials + finalize folded scalar constants
//   arg(natural) = cg*(inv_s*invt)*gg + ce*eu_clamped + cc ;  pH = exp(arg + s8), p = exp(s8)
__global__ __launch_bounds__(256) void k3_fin(const float* __restrict__ alpha,
                                              const float* __restrict__ sigma_w, float* ws){
  __shared__ double ssm[256], sss[256];
  __shared__ float smn[256], smx[256];
  int tid = threadIdx.x;
  const float* part = ws + WS_PE;
  double s = 0.0, ss = 0.0;
  float mn = 3.4e38f, mx = -3.4e38f;
  for (int i2 = tid; i2 < NPART_; i2 += 256){
    s  += (double)part[i2];
    ss += (double)part[NPART_ + i2];
    mn = fminf(mn, part[2*NPART_ + i2]);
    mx = fmaxf(mx, part[3*NPART_ + i2]);
  }
  ssm[tid]=s; sss[tid]=ss; smn[tid]=mn; smx[tid]=mx;
  __syncthreads();
  for (int st = 128; st; st >>= 1){
    if (tid < st){
      ssm[tid] += ssm[tid+st];
      sss[tid] += sss[tid+st];
      smn[tid] = fminf(smn[tid], smn[tid+st]);
      smx[tid] = fmaxf(smx[tid], smx[tid+st]);
    }
    __syncthreads();
  }
  if (tid == 0){
    double N = (double)B_*S_*S_;
    double sum = ssm[0], sumsq = sss[0];
    double mean = sum/N;
    double var  = (sumsq - sum*sum/N) / (N - 1.0);
    float stdv = (float)sqrt(fmax(var, 0.0));
    float m = (float)mean;
    float lo = m - 2.f*stdv, hi = m + 2.f*stdv;
    float cmn = fminf(fmaxf(smn[0], lo), hi);
    float cmx = fminf(fmaxf(smx[0], lo), hi);
    float invr = 1.f/(cmx - cmn + 1e-6f);
    float a = 1.f/(1.f + expf(-alpha[0]));
    float oma = 1.f - a;
    float swv = sigma_w[0];
    float sp = (swv > 20.f) ? swv : log1pf(expf(swv));
    float sg = sp + 0.001f;
    float efac = -0.5f/(sg*sg);
    // folded: arg = efac*(a*cosv + oma*(1-en))
    //  cosv = 0.5*(gg*ii + 1) ; en = (eu-cmn)*invr
    float cg = efac*a*0.5f;
    float ce = -efac*oma*invr;
    float cc = efac*(a*0.5f + oma + oma*invr*cmn);
    float* p = ws + WS_STATS + 8;
    p[0]=lo; p[1]=hi; p[2]=cg; p[3]=ce; p[4]=cc;
  }
}

// K4: MFMA flash pass (8 waves, s-tile 64, no online max) with folded epilogue.
// Writes bf16 pe_event in place of q (US_QB) via clean u16* param.
__global__ __launch_bounds__(512) void k4_flash(const u16* __restrict__ us,
                                                float* __restrict__ ws, u16* qout)
{
  __shared__ __align__(16) u16 SMEM[16384];  // Kls|Xls|XTls|el : 4x8KB
  __shared__ float sqt_l[64], invt_l[64];
  __shared__ float zb[4][2][16];
  u16* Kls  = SMEM;
  u16* Xls  = SMEM + 4096;
  u16* XTls = SMEM + 8192;
  u16* elp  = SMEM + 12288;
  int tid = threadIdx.x, lane = tid & 63, wv = tid >> 6;
  int lg = lane >> 4, lc = lane & 15;
  int ssub = wv >> 1, th = wv & 1;
  int b = blockIdx.y;
  size_t rb = (size_t)b * S_;
  int s0 = blockIdx.x * 64;
  const u16* xb = us + US_XB;
  const u16* qb = us + US_QB;
  const u16* kb = us + US_KB;
  const u16* xt = us + US_XT + (size_t)b*64*2048;
  int srow = s0 + ssub*16 + lc;
  short8 qf0 = *(const short8*)(qb + (rb+srow)*64 + lg*8);
  short8 qf1 = *(const short8*)(qb + (rb+srow)*64 + 32 + lg*8);
  short8 xf0 = *(const short8*)(xb + (rb+srow)*64 + lg*8);
  short8 xf1 = *(const short8*)(xb + (rb+srow)*64 + 32 + lg*8);
  const float* prm = ws + WS_STATS + 8;
  float lo=prm[0], hi=prm[1], cg=prm[2], ce=prm[3], cc=prm[4];
  float sq_s[4], cgis[4];
  #pragma unroll
  for (int r=0;r<4;++r){
    float s = ws[WS_SQ + rb + s0 + ssub*16 + lg*4 + r];
    sq_s[r] = s;
    cgis[r] = cg / fmaxf(sqrtf(s), 1e-12f);   // cg * inv_s[r]
  }
  f32x4 pe[4];
  #pragma unroll
  for (int t=0;t<4;++t){ pe[t][0]=0.f; pe[t][1]=0.f; pe[t][2]=0.f; pe[t][3]=0.f; }
  float zrun[4];
  #pragma unroll
  for (int r=0;r<4;++r) zrun[r]=0.f;

  for (int t0 = 0; t0 < S_; t0 += 64){
    {
      int slot = tid;
      int row = slot>>3, pc = slot&7, lcn = pc ^ (row&7);
      ((short8*)Kls)[slot]  = *(const short8*)(kb + (rb + t0 + row)*64 + lcn*8);
      ((short8*)Xls)[slot]  = *(const short8*)(xb + (rb + t0 + row)*64 + lcn*8);
      ((short8*)XTls)[slot] = *(const short8*)(xt + (size_t)row*2048 + t0 + lcn*8);
    }
    if (tid < 64){
      float s = ws[WS_SQ + rb + t0 + tid];
      sqt_l[tid] = s;
      invt_l[tid] = 1.f / fmaxf(sqrtf(s), 1e-12f);
    }
    __syncthreads();
    f32x4 ga[2], sa[2];
    #pragma unroll
    for (int t=0;t<2;++t){ ga[t][0]=0.f; ga[t][1]=0.f; ga[t][2]=0.f; ga[t][3]=0.f;
                           sa[t][0]=0.f; sa[t][1]=0.f; sa[t][2]=0.f; sa[t][3]=0.f; }
    #pragma unroll
    for (int ts=0; ts<2; ++ts){
      int rowb = (2*th+ts)*16 + lc;
      int sw = rowb & 7;
      short8 bk0 = *(const short8*)(Kls + rowb*64 + ((lg ^ sw)<<3));
      short8 bx0 = *(const short8*)(Xls + rowb*64 + ((lg ^ sw)<<3));
      sa[ts] = MFMA16(qf0, bk0, sa[ts]);
      ga[ts] = MFMA16(xf0, bx0, ga[ts]);
      short8 bk1 = *(const short8*)(Kls + rowb*64 + (((4+lg) ^ sw)<<3));
      short8 bx1 = *(const short8*)(Xls + rowb*64 + (((4+lg) ^ sw)<<3));
      sa[ts] = MFMA16(qf1, bk1, sa[ts]);
      ga[ts] = MFMA16(xf1, bx1, ga[ts]);
    }
    #pragma unroll
    for (int ts=0; ts<2; ++ts){
      int col = (2*th+ts)*16 + lc;
      float sqt = sqt_l[col], invt = invt_l[col];
      #pragma unroll
      for (int r=0;r<4;++r){
        float gg = ga[ts][r];
        float d2 = fmaxf(__builtin_fmaf(-2.f, gg, sq_s[r] + sqt), 0.f);
        float eu = fminf(fmaxf(sqrtf(d2), lo), hi);
        float arg = __builtin_fmaf(cgis[r]*invt, gg, cc);
        arg = __builtin_fmaf(ce, eu, arg);
        float s8 = __builtin_fmaf(sa[ts][r], 0.125f, -8.f);
        float p = __expf(s8);
        float pH = __expf(arg + s8);
        zrun[r] += p;
        int rowl = lg*4 + r;
        int phys = rowl*64 + ((((col>>3) ^ (rowl&7)))<<3) + (col&7);
        elp[ssub*1024 + phys] = f2bf(pH);
      }
    }
    // PV: pe[fs] += E(16x32 window) @ x(32 x 16f)
    {
      int swA = lc & 7;
      short8 Ae = *(const short8*)(elp + ssub*1024 + lc*64 + (((4*th + lg) ^ swA)<<3));
      #pragma unroll
      for (int fs=0; fs<4; ++fs){
        int rowf = fs*16 + lc;
        short8 Bx = *(const short8*)(XTls + rowf*64 + (((4*th + lg) ^ (rowf&7))<<3));
        pe[fs] = MFMA16(Ae, Bx, pe[fs]);
      }
    }
    __syncthreads();
  }
  // z reduce + cross-half combine
  #pragma unroll
  for (int r=0;r<4;++r){
    float z = zrun[r];
    z += __shfl_xor(z, 1, 64);
    z += __shfl_xor(z, 2, 64);
    z += __shfl_xor(z, 4, 64);
    z += __shfl_xor(z, 8, 64);
    if (lc == r) zb[ssub][th][lg*4+r] = z;
  }
  __syncthreads();
  float* tmp = (float*)SMEM;  // 4096 floats scratch (tiles dead now)
  if (th == 1){
    #pragma unroll
    for (int fs=0; fs<4; ++fs)
      #pragma unroll
      for (int r=0;r<4;++r)
        tmp[ssub*1024 + (lg*4+r)*64 + fs*16 + lc] = pe[fs][r];
  }
  __syncthreads();
  if (th == 0){
    float zi[4];
    #pragma unroll
    for (int r=0;r<4;++r) zi[r] = 1.f / (zb[ssub][0][lg*4+r] + zb[ssub][1][lg*4+r]);
    #pragma unroll
    for (int fs=0; fs<4; ++fs)
      #pragma unroll
      for (int r=0;r<4;++r){
        float v = pe[fs][r] + tmp[ssub*1024 + (lg*4+r)*64 + fs*16 + lc];
        qout[US_QB + (rb + s0 + ssub*16 + lg*4 + r)*64 + fs*16 + lc] = f2bf(v * zi[r]);
      }
  }
}

// K5: pe_proj via MFMA (bf16 pe from US_QB, bf16 w_proj from wpb) + both LayerNorms + add
__global__ __launch_bounds__(256) void k5_final(
    const float* __restrict__ w_rel, const float* __restrict__ b_rel,
    const float* __restrict__ b_proj,
    const float* __restrict__ g1, const float* __restrict__ bt1,
    const float* __restrict__ g2, const float* __restrict__ bt2,
    const float* __restrict__ ws, const u16* __restrict__ usb,
    const u16* __restrict__ wpb, float* __restrict__ out)
{
  __shared__ __align__(16) float res[16*512];
  __shared__ float rsl[48];
  __shared__ float g1l[512], b1l[512], g2l[512], b2l[512], brl[512], wrl[1536];
  int tid = threadIdx.x, lane = tid & 63, wv = tid >> 6;
  int lg = lane >> 4, lc = lane & 15;
  int row0 = blockIdx.x * 16;
  const u16* peb = usb + US_QB;
  short8 a0 = *(const short8*)(peb + (size_t)(row0+lc)*64 + lg*8);
  short8 a1 = *(const short8*)(peb + (size_t)(row0+lc)*64 + 32 + lg*8);
  if (tid < 48) rsl[tid] = ws[WS_REL + row0*3 + tid];
  for (int i = tid; i < 512; i += 256){
    g1l[i]=g1[i]; b1l[i]=bt1[i]; g2l[i]=g2[i]; b2l[i]=bt2[i]; brl[i]=b_rel[i];
  }
  for (int i = tid; i < 1536; i += 256) wrl[i] = w_rel[i];
  int wc0 = wv*128;
  #pragma unroll
  for (int cg=0; cg<8; ++cg){
    int d = wc0 + cg*16 + lc;
    short8 b0 = *(const short8*)(wpb + (size_t)d*64 + lg*8);
    short8 b1 = *(const short8*)(wpb + (size_t)d*64 + 32 + lg*8);
    f32x4 acc = {0.f,0.f,0.f,0.f};
    acc = MFMA16(a0, b0, acc);
    acc = MFMA16(a1, b1, acc);
    float bp = b_proj[d];
    #pragma unroll
    for (int r=0;r<4;++r) res[(lg*4+r)*512 + d] = acc[r] + bp;
  }
  __syncthreads();
  #pragma unroll
  for (int j=0;j<4;++j){
    int r = wv*4 + j;
    int rg = row0 + r;
    float s1=0.f, q1=0.f;
    float vals[8];
    #pragma unroll
    for (int i=0;i<8;++i){ float v = res[r*512 + i*64 + lane]; vals[i]=v; s1+=v; q1+=v*v; }
    for (int o=32;o;o>>=1){ s1 += __shfl_xor(s1,o,64); q1 += __shfl_xor(q1,o,64); }
    float mu1 = s1*(1.f/512.f);
    float var1 = q1*(1.f/512.f) - mu1*mu1;
    float rsg1 = rsqrtf(fmaxf(var1, 0.f) + 1e-5f);
    float c0 = rsl[r*3+0], c1 = rsl[r*3+1], c2 = rsl[r*3+2];
    float rv[8]; float s2=0.f, q2=0.f;
    #pragma unroll
    for (int i=0;i<8;++i){
      int d = i*64 + lane;
      float v = c0*wrl[d*3+0] + c1*wrl[d*3+1] + c2*wrl[d*3+2] + 5.f*brl[d];
      rv[i]=v; s2+=v; q2+=v*v;
    }
    for (int o=32;o;o>>=1){ s2 += __shfl_xor(s2,o,64); q2 += __shfl_xor(q2,o,64); }
    float mu2 = s2*(1.f/512.f);
    float var2 = q2*(1.f/512.f) - mu2*mu2;
    float rsg2 = rsqrtf(fmaxf(var2, 0.f) + 1e-5f);
    #pragma unroll
    for (int i=0;i<8;++i){
      int d = i*64 + lane;
      float o1 = (vals[i]-mu1)*rsg1*g2l[d] + b2l[d];
      float o2 = (rv[i]-mu2)*rsg2*g1l[d] + b1l[d];
      out[(size_t)rg*512 + d] = o1 + o2;
    }
  }
}

extern "C" void kernel_launch(void* const* d_in, const int* in_sizes, int n_in,
                              void* d_out, int out_size, void* d_ws, size_t ws_size,
                              hipStream_t stream)
{
  const float* x      = (const float*)d_in[0];
  const float* w_rel  = (const float*)d_in[1];
  const float* b_rel  = (const float*)d_in[2];
  const float* w_proj = (const float*)d_in[3];
  const float* b_proj = (const float*)d_in[4];
  const float* g1     = (const float*)d_in[5];
  const float* bt1    = (const float*)d_in[6];
  const float* g2     = (const float*)d_in[7];
  const float* bt2    = (const float*)d_in[8];
  const float* alpha  = (const float*)d_in[9];
  const float* sigma_w= (const float*)d_in[10];
  const float* wq     = (const float*)d_in[11];
  const float* bq     = (const float*)d_in[12];
  const float* wk     = (const float*)d_in[13];
  const float* bk     = (const float*)d_in[14];
  const float* scale_w= (const float*)d_in[15];
  float* wsf = (float*)d_ws;
  u16*  usb = (u16*)(wsf + US_BASE_FLOATS);
  u16*  wpb = (u16*)(wsf + WS_WPB);
  float* out = (float*)d_out;

  hipLaunchKernelGGL(k1_prep, dim3(BS_/16), dim3(256), 0, stream,
                     x, wq, bq, wk, bk, scale_w, w_proj, wsf, usb, wpb);
  hipLaunchKernelGGL(k2_stats, dim3(NTILE_, B_), dim3(256), 0, stream, usb, wsf);
  hipLaunchKernelGGL(k3_fin, dim3(1), dim3(256), 0, stream, alpha, sigma_w, wsf);
  hipLaunchKernelGGL(k4_flash, dim3(S_/64, B_), dim3(512), 0, stream, usb, wsf, usb);
  hipLaunchKernelGGL(k5_final, dim3(BS_/16), dim3(256), 0, stream,
                     w_rel, b_rel, b_proj, g1, bt1, g2, bt2, wsf, usb, wpb, out);
}

// Round 8
// 202.701 us; speedup vs baseline: 5.9048x; 1.0692x over previous
//
#include <hip/hip_runtime.h>
#include <math.h>

#define B_ 8
#define S_ 2048
#define F_ 64
#define D_ 512
#define NS_ 5
#define BS_ (B_*S_)
#define NTILE_ 528
#define NPART_ (NTILE_*B_)

typedef unsigned short u16;
typedef __attribute__((ext_vector_type(8))) short short8;
typedef __attribute__((ext_vector_type(4))) float f32x4;

// float-region offsets (in floats)
#define WS_SQ    0
#define WS_REL   (BS_)
#define WS_PE    (4*BS_)       // k2 partials [0,16896); bf16 w_proj at +20480 (u16 view)
#define WS_WPB   (WS_PE + 20480)
#define WS_STATS (68*BS_)
#define US_BASE_FLOATS (68*BS_ + 16)
// ushort-region offsets (in ushorts, from usb)
#define US_XB 0
#define US_QB (BS_*64)
#define US_KB (2*BS_*64)
#define US_XT (3*BS_*64)

#define MFMA16(a,b,c) __builtin_amdgcn_mfma_f32_16x16x32_bf16(a,b,c,0,0,0)

__device__ __forceinline__ u16 f2bf(float f){
  unsigned u = __float_as_uint(f);
  return (u16)((u + 0x7FFFu + ((u>>16)&1u)) >> 16);
}
// f32-tile swizzle used by k1
__device__ __forceinline__ int swz_phys(int row, int c){ return row*64 + (((c ^ (row & 15))) << 2); }

// K1: q/k (fp32 compute -> bf16 store), sq, rel sums, xb16, xT16, w_proj bf16 (blocks 0..31)
__global__ __launch_bounds__(256) void k1_prep(
    const float* __restrict__ x, const float* __restrict__ wq, const float* __restrict__ bq,
    const float* __restrict__ wk, const float* __restrict__ bk,
    const float* __restrict__ scale_w, const float* __restrict__ wp,
    float* __restrict__ ws, u16* __restrict__ usb, u16* __restrict__ wpb)
{
  __shared__ __align__(16) float xl[16*68];
  __shared__ __align__(16) float wql[4096];
  __shared__ __align__(16) float wkl[4096];
  int tid = threadIdx.x, lane = tid & 63, wv = tid >> 6;
  int row0 = blockIdx.x * 16;
  {
    int r = tid >> 4, c = tid & 15;
    *(float4*)(xl + r*68 + c*4) = *(const float4*)(x + (size_t)(row0 + r)*F_ + c*4);
  }
  for (int i = 0; i < 4; ++i){
    int idx = tid + i*256;
    int g = idx >> 4, c = idx & 15;
    float4 v = *(const float4*)(wq + g*F_ + c*4);
    int pb = swz_phys(g, c);
    wql[pb]=v.x; wql[pb+1]=v.y; wql[pb+2]=v.z; wql[pb+3]=v.w;
    float4 u = *(const float4*)(wk + g*F_ + c*4);
    wkl[pb]=u.x; wkl[pb+1]=u.y; wkl[pb+2]=u.z; wkl[pb+3]=u.w;
  }
  // w_proj bf16 conversion (independent work, blocks 0..31)
  if (blockIdx.x < 32){
    int i2 = (blockIdx.x*256 + tid)*4;
    float4 v = *(const float4*)(wp + i2);
    uint2 pk2;
    pk2.x = (unsigned)f2bf(v.x) | ((unsigned)f2bf(v.y)<<16);
    pk2.y = (unsigned)f2bf(v.z) | ((unsigned)f2bf(v.w)<<16);
    *(uint2*)(wpb + i2) = pk2;
  }
  __syncthreads();
  int g = lane;
  int swl = g & 15;
  float qa[4], ka[4];
  #pragma unroll
  for (int j=0;j<4;++j){ qa[j]=bq[g]; ka[j]=bk[g]; }
  #pragma unroll
  for (int c=0;c<16;++c){
    float4 wqv = *(const float4*)(wql + g*64 + ((c ^ swl)<<2));
    float4 wkv = *(const float4*)(wkl + g*64 + ((c ^ swl)<<2));
    #pragma unroll
    for (int j=0;j<4;++j){
      float4 xv = *(const float4*)(xl + (wv*4+j)*68 + c*4);
      qa[j] += xv.x*wqv.x + xv.y*wqv.y + xv.z*wqv.z + xv.w*wqv.w;
      ka[j] += xv.x*wkv.x + xv.y*wkv.y + xv.z*wkv.z + xv.w*wkv.w;
    }
  }
  #pragma unroll
  for (int j=0;j<4;++j){
    int rg = row0 + wv*4 + j;
    usb[US_QB + (size_t)rg*64 + g] = f2bf(qa[j]);
    usb[US_KB + (size_t)rg*64 + g] = f2bf(ka[j]);
  }
  #pragma unroll
  for (int j=0;j<4;++j){
    int r = wv*4 + j;
    float v = xl[r*68 + lane];
    float s = v*v;
    for (int o=32;o;o>>=1) s += __shfl_xor(s, o, 64);
    if (lane == 0) ws[WS_SQ + row0 + r] = s;
  }
  #pragma unroll
  for (int j=0;j<4;++j){
    int r = wv*4 + j;
    int rg = row0 + r;
    int b = rg >> 11, s_loc = rg & (S_-1);
    float d0 = xl[r*68 + 0], e0 = xl[r*68 + 1];
    float dd = 0.f, de = 0.f, wd = 0.f;
    int n = lane + 1;
    if (lane < NS_ && s_loc >= n){
      const float* xp = x + ((size_t)(b*S_ + s_loc - n))*F_;
      float dp_ = xp[0], ep = xp[1];
      dd = dp_ - d0;
      de = ep - e0;
      wd = scale_w[lane] * __expf(-fabsf(dd) * (1.0f/(float)(1<<n)));
    }
    for (int o=4;o;o>>=1){
      dd += __shfl_down(dd, o, 64);
      de += __shfl_down(de, o, 64);
      wd += __shfl_down(wd, o, 64);
    }
    if (lane == 0){
      ws[WS_REL + rg*3+0] = dd;
      ws[WS_REL + rg*3+1] = de;
      ws[WS_REL + rg*3+2] = wd;
    }
  }
  // bf16 x (row-major)
  {
    int r = tid >> 4, cb = (tid & 15)*4;
    unsigned w0 = (unsigned)f2bf(xl[r*68+cb])   | ((unsigned)f2bf(xl[r*68+cb+1])<<16);
    unsigned w1 = (unsigned)f2bf(xl[r*68+cb+2]) | ((unsigned)f2bf(xl[r*68+cb+3])<<16);
    uint2 pk; pk.x = w0; pk.y = w1;
    *(uint2*)(usb + US_XB + (size_t)(row0+r)*64 + cb) = pk;
  }
  // bf16 x transposed per batch: xT[b][f][t]
  {
    int f = tid & 63, rg4 = (tid >> 6)*4;
    unsigned wa = (unsigned)f2bf(xl[(rg4+0)*68+f]) | ((unsigned)f2bf(xl[(rg4+1)*68+f])<<16);
    unsigned wb = (unsigned)f2bf(xl[(rg4+2)*68+f]) | ((unsigned)f2bf(xl[(rg4+3)*68+f])<<16);
    uint2 pk; pk.x = wa; pk.y = wb;
    int bb = row0 >> 11;
    int tloc = (row0 & (S_-1)) + rg4;
    *(uint2*)(usb + US_XT + (size_t)bb*64*2048 + (size_t)f*2048 + tloc) = pk;
  }
}

// K2: euclid stats via MFMA Gram, upper-triangle tiles only (off-diag weight 2).
__global__ __launch_bounds__(256) void k2_stats(const u16* __restrict__ us, float* __restrict__ ws)
{
  __shared__ __align__(16) u16 Xls[4096];
  __shared__ float sqs_l[64], sqt_l[64];
  __shared__ float rsum[4], rss[4], rmn[4], rmx[4];
  int tid = threadIdx.x, lane = tid & 63, wv = tid >> 6;
  int lg = lane >> 4, lc = lane & 15;
  int b = blockIdx.y;
  int rem = blockIdx.x, i = 0;
  while (rem >= 32 - i){ rem -= 32 - i; ++i; }
  int j = i + rem;
  int s0 = i*64, t0 = j*64;
  size_t rb = (size_t)b * S_;
  const u16* xb = us + US_XB;
  #pragma unroll
  for (int p2=0;p2<2;++p2){
    int slot = tid + p2*256;
    int row = slot>>3, pc = slot&7, lcn = pc ^ (row&7);
    ((short8*)Xls)[slot] = *(const short8*)(xb + (rb + t0 + row)*64 + lcn*8);
  }
  if (tid < 64) sqs_l[tid] = ws[WS_SQ + rb + s0 + tid];
  else if (tid < 128) sqt_l[tid-64] = ws[WS_SQ + rb + t0 + (tid-64)];
  short8 a0 = *(const short8*)(xb + (rb + s0 + wv*16 + lc)*64 + lg*8);
  short8 a1 = *(const short8*)(xb + (rb + s0 + wv*16 + lc)*64 + 32 + lg*8);
  __syncthreads();
  f32x4 acc[4];
  #pragma unroll
  for (int t=0;t<4;++t){ acc[t][0]=0.f; acc[t][1]=0.f; acc[t][2]=0.f; acc[t][3]=0.f; }
  #pragma unroll
  for (int ts=0; ts<4; ++ts){
    int rowb = ts*16 + lc;
    int sw = rowb & 7;
    short8 b0 = *(const short8*)(Xls + rowb*64 + ((lg ^ sw)<<3));
    short8 b1 = *(const short8*)(Xls + rowb*64 + (((4+lg) ^ sw)<<3));
    acc[ts] = MFMA16(a0, b0, acc[ts]);
    acc[ts] = MFMA16(a1, b1, acc[ts]);
  }
  float sq_s[4];
  #pragma unroll
  for (int r=0;r<4;++r) sq_s[r] = sqs_l[wv*16 + lg*4 + r];
  float lsum=0.f, lss=0.f, lmn=3.4e38f, lmx=-3.4e38f;
  #pragma unroll
  for (int ts=0; ts<4; ++ts){
    float sqt = sqt_l[ts*16 + lc];
    #pragma unroll
    for (int r=0;r<4;++r){
      float gg = acc[ts][r];
      float d2 = sq_s[r] + sqt - 2.f*gg;
      d2 = fmaxf(d2, 0.f);
      float eu = d2 > 0.f ? sqrtf(d2) : 0.f;
      lsum += eu; lss += eu*eu;
      lmn = fminf(lmn, eu); lmx = fmaxf(lmx, eu);
    }
  }
  for (int o=32;o;o>>=1){
    lsum += __shfl_xor(lsum, o, 64);
    lss  += __shfl_xor(lss, o, 64);
    lmn = fminf(lmn, __shfl_xor(lmn, o, 64));
    lmx = fmaxf(lmx, __shfl_xor(lmx, o, 64));
  }
  if (lane == 0){ rsum[wv]=lsum; rss[wv]=lss; rmn[wv]=lmn; rmx[wv]=lmx; }
  __syncthreads();
  if (tid == 0){
    float bs=0.f, bss=0.f, bmn=3.4e38f, bmx=-3.4e38f;
    for (int w2=0;w2<4;++w2){ bs+=rsum[w2]; bss+=rss[w2]; bmn=fminf(bmn,rmn[w2]); bmx=fmaxf(bmx,rmx[w2]); }
    float wgt = (i==j) ? 1.f : 2.f;
    float* part = ws + WS_PE;
    int bid = blockIdx.y * NTILE_ + blockIdx.x;
    part[bid]           = bs*wgt;
    part[NPART_ + bid]  = bss*wgt;
    part[2*NPART_ + bid]= bmn;
    part[3*NPART_ + bid]= bmx;
  }
}

// K3: reduce k2 partials + finalize folded scalar constants
__global__ __launch_bounds__(256) void k3_fin(const float* __restrict__ alpha,
                                              const float* __restrict__ sigma_w, float* ws){
  __shared__ double ssm[256], sss[256];
  __shared__ float smn[256], smx[256];
  int tid = threadIdx.x;
  const float* part = ws + WS_PE;
  double s = 0.0, ss = 0.0;
  float mn = 3.4e38f, mx = -3.4e38f;
  for (int i2 = tid; i2 < NPART_; i2 += 256){
    s  += (double)part[i2];
    ss += (double)part[NPART_ + i2];
    mn = fminf(mn, part[2*NPART_ + i2]);
    mx = fmaxf(mx, part[3*NPART_ + i2]);
  }
  ssm[tid]=s; sss[tid]=ss; smn[tid]=mn; smx[tid]=mx;
  __syncthreads();
  for (int st = 128; st; st >>= 1){
    if (tid < st){
      ssm[tid] += ssm[tid+st];
      sss[tid] += sss[tid+st];
      smn[tid] = fminf(smn[tid], smn[tid+st]);
      smx[tid] = fmaxf(smx[tid], smx[tid+st]);
    }
    __syncthreads();
  }
  if (tid == 0){
    double N = (double)B_*S_*S_;
    double sum = ssm[0], sumsq = sss[0];
    double mean = sum/N;
    double var  = (sumsq - sum*sum/N) / (N - 1.0);
    float stdv = (float)sqrt(fmax(var, 0.0));
    float m = (float)mean;
    float lo = m - 2.f*stdv, hi = m + 2.f*stdv;
    float cmn = fminf(fmaxf(smn[0], lo), hi);
    float cmx = fminf(fmaxf(smx[0], lo), hi);
    float invr = 1.f/(cmx - cmn + 1e-6f);
    float a = 1.f/(1.f + expf(-alpha[0]));
    float oma = 1.f - a;
    float swv = sigma_w[0];
    float sp = (swv > 20.f) ? swv : log1pf(expf(swv));
    float sg = sp + 0.001f;
    float efac = -0.5f/(sg*sg);
    float cg = efac*a*0.5f;
    float ce = -efac*oma*invr;
    float cc = efac*(a*0.5f + oma + oma*invr*cmn);
    float* p = ws + WS_STATS + 8;
    p[0]=lo; p[1]=hi; p[2]=cg; p[3]=ce; p[4]=cc;
  }
}

// K4: MFMA flash pass, t-split (grid.z = 2): each block does half the K-tiles and
// writes unnormalized f32 pe-partials + z-partials into its k5-block's private
// slice of d_out (scratch): base = rowblk*8192; pe at +h*2048, z at +4096+h*16.
__global__ __launch_bounds__(512) void k4_flash(const u16* __restrict__ us,
                                                const float* __restrict__ ws,
                                                float* __restrict__ outsc)
{
  __shared__ __align__(16) u16 SMEM[16384];  // Kls|Xls|XTls|el : 4x8KB
  __shared__ float sqt_l[64], invt_l[64];
  __shared__ float zb[4][2][16];
  u16* Kls  = SMEM;
  u16* Xls  = SMEM + 4096;
  u16* XTls = SMEM + 8192;
  u16* elp  = SMEM + 12288;
  int tid = threadIdx.x, lane = tid & 63, wv = tid >> 6;
  int lg = lane >> 4, lc = lane & 15;
  int ssub = wv >> 1, th = wv & 1;
  int b = blockIdx.y;
  int h = blockIdx.z;
  size_t rb = (size_t)b * S_;
  int s0 = blockIdx.x * 64;
  const u16* xb = us + US_XB;
  const u16* qb = us + US_QB;
  const u16* kb = us + US_KB;
  const u16* xt = us + US_XT + (size_t)b*64*2048;
  int srow = s0 + ssub*16 + lc;
  short8 qf0 = *(const short8*)(qb + (rb+srow)*64 + lg*8);
  short8 qf1 = *(const short8*)(qb + (rb+srow)*64 + 32 + lg*8);
  short8 xf0 = *(const short8*)(xb + (rb+srow)*64 + lg*8);
  short8 xf1 = *(const short8*)(xb + (rb+srow)*64 + 32 + lg*8);
  const float* prm = ws + WS_STATS + 8;
  float lo=prm[0], hi=prm[1], cg=prm[2], ce=prm[3], cc=prm[4];
  float sq_s[4], cgis[4];
  #pragma unroll
  for (int r=0;r<4;++r){
    float s = ws[WS_SQ + rb + s0 + ssub*16 + lg*4 + r];
    sq_s[r] = s;
    cgis[r] = cg / fmaxf(sqrtf(s), 1e-12f);
  }
  f32x4 pe[4];
  #pragma unroll
  for (int t=0;t<4;++t){ pe[t][0]=0.f; pe[t][1]=0.f; pe[t][2]=0.f; pe[t][3]=0.f; }
  float zrun[4];
  #pragma unroll
  for (int r=0;r<4;++r) zrun[r]=0.f;

  int tbeg = h * (S_/2), tend = tbeg + (S_/2);
  for (int t0 = tbeg; t0 < tend; t0 += 64){
    {
      int slot = tid;
      int row = slot>>3, pc = slot&7, lcn = pc ^ (row&7);
      ((short8*)Kls)[slot]  = *(const short8*)(kb + (rb + t0 + row)*64 + lcn*8);
      ((short8*)Xls)[slot]  = *(const short8*)(xb + (rb + t0 + row)*64 + lcn*8);
      ((short8*)XTls)[slot] = *(const short8*)(xt + (size_t)row*2048 + t0 + lcn*8);
    }
    if (tid < 64){
      float s = ws[WS_SQ + rb + t0 + tid];
      sqt_l[tid] = s;
      invt_l[tid] = 1.f / fmaxf(sqrtf(s), 1e-12f);
    }
    __syncthreads();
    f32x4 ga[2], sa[2];
    #pragma unroll
    for (int t=0;t<2;++t){ ga[t][0]=0.f; ga[t][1]=0.f; ga[t][2]=0.f; ga[t][3]=0.f;
                           sa[t][0]=0.f; sa[t][1]=0.f; sa[t][2]=0.f; sa[t][3]=0.f; }
    #pragma unroll
    for (int ts=0; ts<2; ++ts){
      int rowb = (2*th+ts)*16 + lc;
      int sw = rowb & 7;
      short8 bk0 = *(const short8*)(Kls + rowb*64 + ((lg ^ sw)<<3));
      short8 bx0 = *(const short8*)(Xls + rowb*64 + ((lg ^ sw)<<3));
      sa[ts] = MFMA16(qf0, bk0, sa[ts]);
      ga[ts] = MFMA16(xf0, bx0, ga[ts]);
      short8 bk1 = *(const short8*)(Kls + rowb*64 + (((4+lg) ^ sw)<<3));
      short8 bx1 = *(const short8*)(Xls + rowb*64 + (((4+lg) ^ sw)<<3));
      sa[ts] = MFMA16(qf1, bk1, sa[ts]);
      ga[ts] = MFMA16(xf1, bx1, ga[ts]);
    }
    #pragma unroll
    for (int ts=0; ts<2; ++ts){
      int col = (2*th+ts)*16 + lc;
      float sqt = sqt_l[col], invt = invt_l[col];
      #pragma unroll
      for (int r=0;r<4;++r){
        float gg = ga[ts][r];
        float d2 = fmaxf(__builtin_fmaf(-2.f, gg, sq_s[r] + sqt), 0.f);
        float eu = fminf(fmaxf(sqrtf(d2), lo), hi);
        float arg = __builtin_fmaf(cgis[r]*invt, gg, cc);
        arg = __builtin_fmaf(ce, eu, arg);
        float s8 = __builtin_fmaf(sa[ts][r], 0.125f, -8.f);
        float p = __expf(s8);
        float pH = __expf(arg + s8);
        zrun[r] += p;
        int rowl = lg*4 + r;
        int phys = rowl*64 + ((((col>>3) ^ (rowl&7)))<<3) + (col&7);
        elp[ssub*1024 + phys] = f2bf(pH);
      }
    }
    // PV: pe[fs] += E(16x32 window) @ x(32 x 16f)
    {
      int swA = lc & 7;
      short8 Ae = *(const short8*)(elp + ssub*1024 + lc*64 + (((4*th + lg) ^ swA)<<3));
      #pragma unroll
      for (int fs=0; fs<4; ++fs){
        int rowf = fs*16 + lc;
        short8 Bx = *(const short8*)(XTls + rowf*64 + (((4*th + lg) ^ (rowf&7))<<3));
        pe[fs] = MFMA16(Ae, Bx, pe[fs]);
      }
    }
    __syncthreads();
  }
  // z reduce (per row, over this block's t-half)
  #pragma unroll
  for (int r=0;r<4;++r){
    float z = zrun[r];
    z += __shfl_xor(z, 1, 64);
    z += __shfl_xor(z, 2, 64);
    z += __shfl_xor(z, 4, 64);
    z += __shfl_xor(z, 8, 64);
    if (lc == r) zb[ssub][th][lg*4+r] = z;
  }
  __syncthreads();
  float* tmp = (float*)SMEM;  // 4096 floats scratch (tiles dead now)
  if (th == 1){
    #pragma unroll
    for (int fs=0; fs<4; ++fs)
      #pragma unroll
      for (int r=0;r<4;++r)
        tmp[ssub*1024 + (lg*4+r)*64 + fs*16 + lc] = pe[fs][r];
  }
  __syncthreads();
  if (th == 0){
    size_t base = (((rb + s0) >> 4) + ssub) * 8192;   // k5-block slice
    float* sc = outsc + base + (size_t)h*2048;
    #pragma unroll
    for (int fs=0; fs<4; ++fs)
      #pragma unroll
      for (int r=0;r<4;++r){
        float v = pe[fs][r] + tmp[ssub*1024 + (lg*4+r)*64 + fs*16 + lc];
        sc[(lg*4+r)*64 + fs*16 + lc] = v;
      }
    if (lg == 0)
      outsc[base + 4096 + h*16 + lc] = zb[ssub][0][lc] + zb[ssub][1][lc];
  }
}

// K5: combine pe partials from scratch (in d_out), MFMA pe_proj + both LayerNorms + add.
// out is read (scratch, block-private slice) then overwritten — no restrict.
__global__ __launch_bounds__(256) void k5_final(
    const float* __restrict__ w_rel, const float* __restrict__ b_rel,
    const float* __restrict__ b_proj,
    const float* __restrict__ g1, const float* __restrict__ bt1,
    const float* __restrict__ g2, const float* __restrict__ bt2,
    const float* __restrict__ ws, const u16* __restrict__ wpb, float* out)
{
  __shared__ __align__(16) float res[16*512];
  __shared__ float rsl[48];
  __shared__ float g1l[512], b1l[512], g2l[512], b2l[512], brl[512], wrl[1536];
  int tid = threadIdx.x, lane = tid & 63, wv = tid >> 6;
  int lg = lane >> 4, lc = lane & 15;
  int row0 = blockIdx.x * 16;
  size_t base5 = (size_t)blockIdx.x * 8192;
  float zi = 1.f / (out[base5 + 4096 + lc] + out[base5 + 4096 + 16 + lc]);
  short8 a0, a1;
  {
    const float* p0 = out + base5 + (size_t)lc*64 + lg*8;
    const float* p1 = p0 + 2048;
    float4 u0 = *(const float4*)(p0);
    float4 u1 = *(const float4*)(p0 + 4);
    float4 v0 = *(const float4*)(p1);
    float4 v1 = *(const float4*)(p1 + 4);
    a0[0]=(short)f2bf((u0.x+v0.x)*zi); a0[1]=(short)f2bf((u0.y+v0.y)*zi);
    a0[2]=(short)f2bf((u0.z+v0.z)*zi); a0[3]=(short)f2bf((u0.w+v0.w)*zi);
    a0[4]=(short)f2bf((u1.x+v1.x)*zi); a0[5]=(short)f2bf((u1.y+v1.y)*zi);
    a0[6]=(short)f2bf((u1.z+v1.z)*zi); a0[7]=(short)f2bf((u1.w+v1.w)*zi);
    const float* q0 = p0 + 32;
    const float* q1 = p1 + 32;
    float4 w0 = *(const float4*)(q0);
    float4 w1 = *(const float4*)(q0 + 4);
    float4 y0 = *(const float4*)(q1);
    float4 y1 = *(const float4*)(q1 + 4);
    a1[0]=(short)f2bf((w0.x+y0.x)*zi); a1[1]=(short)f2bf((w0.y+y0.y)*zi);
    a1[2]=(short)f2bf((w0.z+y0.z)*zi); a1[3]=(short)f2bf((w0.w+y0.w)*zi);
    a1[4]=(short)f2bf((w1.x+y1.x)*zi); a1[5]=(short)f2bf((w1.y+y1.y)*zi);
    a1[6]=(short)f2bf((w1.z+y1.z)*zi); a1[7]=(short)f2bf((w1.w+y1.w)*zi);
  }
  if (tid < 48) rsl[tid] = ws[WS_REL + row0*3 + tid];
  for (int i = tid; i < 512; i += 256){
    g1l[i]=g1[i]; b1l[i]=bt1[i]; g2l[i]=g2[i]; b2l[i]=bt2[i]; brl[i]=b_rel[i];
  }
  for (int i = tid; i < 1536; i += 256) wrl[i] = w_rel[i];
  int wc0 = wv*128;
  #pragma unroll
  for (int cgi=0; cgi<8; ++cgi){
    int d = wc0 + cgi*16 + lc;
    short8 b0 = *(const short8*)(wpb + (size_t)d*64 + lg*8);
    short8 b1 = *(const short8*)(wpb + (size_t)d*64 + 32 + lg*8);
    f32x4 acc = {0.f,0.f,0.f,0.f};
    acc = MFMA16(a0, b0, acc);
    acc = MFMA16(a1, b1, acc);
    float bp = b_proj[d];
    #pragma unroll
    for (int r=0;r<4;++r) res[(lg*4+r)*512 + d] = acc[r] + bp;
  }
  __syncthreads();
  #pragma unroll
  for (int j=0;j<4;++j){
    int r = wv*4 + j;
    int rg = row0 + r;
    float s1=0.f, q1=0.f;
    float vals[8];
    #pragma unroll
    for (int i=0;i<8;++i){ float v = res[r*512 + i*64 + lane]; vals[i]=v; s1+=v; q1+=v*v; }
    for (int o=32;o;o>>=1){ s1 += __shfl_xor(s1,o,64); q1 += __shfl_xor(q1,o,64); }
    float mu1 = s1*(1.f/512.f);
    float var1 = q1*(1.f/512.f) - mu1*mu1;
    float rsg1 = rsqrtf(fmaxf(var1, 0.f) + 1e-5f);
    float c0 = rsl[r*3+0], c1 = rsl[r*3+1], c2 = rsl[r*3+2];
    float rv[8]; float s2=0.f, q2=0.f;
    #pragma unroll
    for (int i=0;i<8;++i){
      int d = i*64 + lane;
      float v = c0*wrl[d*3+0] + c1*wrl[d*3+1] + c2*wrl[d*3+2] + 5.f*brl[d];
      rv[i]=v; s2+=v; q2+=v*v;
    }
    for (int o=32;o;o>>=1){ s2 += __shfl_xor(s2,o,64); q2 += __shfl_xor(q2,o,64); }
    float mu2 = s2*(1.f/512.f);
    float var2 = q2*(1.f/512.f) - mu2*mu2;
    float rsg2 = rsqrtf(fmaxf(var2, 0.f) + 1e-5f);
    #pragma unroll
    for (int i=0;i<8;++i){
      int d = i*64 + lane;
      float o1 = (vals[i]-mu1)*rsg1*g2l[d] + b2l[d];
      float o2 = (rv[i]-mu2)*rsg2*g1l[d] + b1l[d];
      out[(size_t)rg*512 + d] = o1 + o2;
    }
  }
}

extern "C" void kernel_launch(void* const* d_in, const int* in_sizes, int n_in,
                              void* d_out, int out_size, void* d_ws, size_t ws_size,
                              hipStream_t stream)
{
  const float* x      = (const float*)d_in[0];
  const float* w_rel  = (const float*)d_in[1];
  const float* b_rel  = (const float*)d_in[2];
  const float* w_proj = (const float*)d_in[3];
  const float* b_proj = (const float*)d_in[4];
  const float* g1     = (const float*)d_in[5];
  const float* bt1    = (const float*)d_in[6];
  const float* g2     = (const float*)d_in[7];
  const float* bt2    = (const float*)d_in[8];
  const float* alpha  = (const float*)d_in[9];
  const float* sigma_w= (const float*)d_in[10];
  const float* wq     = (const float*)d_in[11];
  const float* bq     = (const float*)d_in[12];
  const float* wk     = (const float*)d_in[13];
  const float* bk     = (const float*)d_in[14];
  const float* scale_w= (const float*)d_in[15];
  float* wsf = (float*)d_ws;
  u16*  usb = (u16*)(wsf + US_BASE_FLOATS);
  u16*  wpb = (u16*)(wsf + WS_WPB);
  float* out = (float*)d_out;

  hipLaunchKernelGGL(k1_prep, dim3(BS_/16), dim3(256), 0, stream,
                     x, wq, bq, wk, bk, scale_w, w_proj, wsf, usb, wpb);
  hipLaunchKernelGGL(k2_stats, dim3(NTILE_, B_), dim3(256), 0, stream, usb, wsf);
  hipLaunchKernelGGL(k3_fin, dim3(1), dim3(256), 0, stream, alpha, sigma_w, wsf);
  hipLaunchKernelGGL(k4_flash, dim3(S_/64, B_, 2), dim3(512), 0, stream, usb, wsf, out);
  hipLaunchKernelGGL(k5_final, dim3(BS_/16), dim3(256), 0, stream,
                     w_rel, b_rel, b_proj, g1, bt1, g2, bt2, wsf, wpb, out);
}